// Round 1
// baseline (26096.228 us; speedup 1.0000x reference)
//
#include <hip/hip_runtime.h>
#include <math.h>
#include <stddef.h>

#define NTWO 640
#define DXN 256
#define DNLN 128
#define DINN 64
#define DOUTN 64
#define BATCHN 512
#define HORN 512
#define NB 4
#define EPSV 1.0e-3

// ---------------- precompute kernels (one-time, f64) ----------------

// H = X^T X + eps*I  (640x640, f64 accumulate)
__global__ void k_xtx(const float* __restrict__ X, double* __restrict__ H) {
  __shared__ float sA[16][17];
  __shared__ float sB[16][17];
  const int tx = threadIdx.x, ty = threadIdx.y;
  const int bi = blockIdx.y * 16, bj = blockIdx.x * 16;
  double acc = 0.0;
  for (int k0 = 0; k0 < NTWO; k0 += 16) {
    sA[ty][tx] = X[(k0 + ty) * NTWO + bi + tx];
    sB[ty][tx] = X[(k0 + ty) * NTWO + bj + tx];
    __syncthreads();
#pragma unroll
    for (int kk = 0; kk < 16; ++kk)
      acc += (double)sA[kk][ty] * (double)sB[kk][tx];
    __syncthreads();
  }
  const int i = bi + ty, j = bj + tx;
  if (i == j) acc += EPSV;
  H[i * NTWO + j] = acc;
}

// E = 0.5*(H11 + H33 + Y - Y^T)  (256x256 f64)
__global__ void k_build_e(const double* __restrict__ H, const float* __restrict__ Y,
                          double* __restrict__ E) {
  int idx = blockIdx.x * 256 + threadIdx.x;
  int i = idx >> 8, j = idx & 255;
  E[idx] = 0.5 * (H[i * NTWO + j] + H[(384 + i) * NTWO + 384 + j]
                  + (double)Y[i * 256 + j] - (double)Y[j * 256 + i]);
}

// sc_i = 2*log2(e) / Lam_i,  Lam_i = 0.5*H22[i][i]
__global__ void k_sc(const double* __restrict__ H, double* __restrict__ sc) {
  int i = threadIdx.x;
  if (i < 128) {
    double lam = 0.5 * H[(256 + i) * NTWO + 256 + i];
    sc[i] = 2.8853900817779268 / lam;
  }
}

__global__ void k_cast_f2d(const float* __restrict__ s, double* __restrict__ d, int n) {
  int i = blockIdx.x * 256 + threadIdx.x;
  if (i < n) d[i] = (double)s[i];
}

__global__ void k_eye2(double* __restrict__ A) {
  int idx = blockIdx.x * 256 + threadIdx.x;  // 128*128
  int r = idx >> 7, c = idx & 127;
  A[idx] = (r == c) ? 2.0 : 0.0;
}

// Dext (64x448): zeros with D21 in cols [256,384)
__global__ void k_dext(const float* __restrict__ D21, double* __restrict__ Dx) {
  int idx = blockIdx.x * 256 + threadIdx.x;  // 64*448
  int r = idx / 448, c = idx % 448;
  double v = 0.0;
  if (c >= 256 && c < 384) v = (double)D21[r * 128 + (c - 256)];
  Dx[idx] = v;
}

// approximate fp32 inverse of a 128x128 block via in-place Gauss-Jordan (no pivot;
// valid since symmetric part is PD). Refined to f64 accuracy by Newton-Schulz.
__global__ void k_ginv32(const double* __restrict__ A, int lda, float* __restrict__ Out) {
  __shared__ float M[128 * 128];
  const int tid = threadIdx.x;
  for (int i = tid; i < 128 * 128; i += 256)
    M[i] = (float)A[(i >> 7) * lda + (i & 127)];
  __syncthreads();
  for (int k = 0; k < 128; ++k) {
    float ip = 1.0f / M[k * 128 + k];  // all threads read same value (post-barrier)
    __syncthreads();
    if (tid < 128) {
      float v = M[k * 128 + tid];
      M[k * 128 + tid] = (tid == k) ? ip : v * ip;
    }
    __syncthreads();
    const int i0 = tid >> 1, half = tid & 1;
    float f = (i0 != k) ? M[i0 * 128 + k] : 0.0f;
    __syncthreads();
    if (i0 != k) {
      const float* rk = M + k * 128;
      float* ri = M + i0 * 128;
      const int j0 = half * 64;
#pragma unroll 8
      for (int j = j0; j < j0 + 64; ++j) {
        float v = (j == k) ? 0.0f : ri[j];
        ri[j] = v - f * rk[j];
      }
    }
    __syncthreads();
  }
  for (int i = tid; i < 128 * 128; i += 256) Out[i] = M[i];
}

// C[MxN] = alpha*A@B + beta*D   (f64; M,N,K multiples of 16)
__global__ void k_dgemm(int M, int N, int K,
                        const double* __restrict__ A, int lda,
                        const double* __restrict__ B, int ldb,
                        double alpha,
                        const double* __restrict__ D, int ldd, double beta,
                        double* __restrict__ C, int ldc) {
  __shared__ double sA[16][17];
  __shared__ double sB[16][17];
  const int tx = threadIdx.x, ty = threadIdx.y;
  const int row = blockIdx.y * 16 + ty, col = blockIdx.x * 16 + tx;
  double acc = 0.0;
  for (int k0 = 0; k0 < K; k0 += 16) {
    sA[ty][tx] = A[row * lda + k0 + tx];
    sB[ty][tx] = B[(k0 + ty) * ldb + col];
    __syncthreads();
#pragma unroll
    for (int kk = 0; kk < 16; ++kk) acc += sA[ty][kk] * sB[kk][tx];
    __syncthreads();
  }
  double v = alpha * acc;
  if (beta != 0.0) v += beta * D[row * ldd + col];
  C[row * ldc + col] = v;
}

__global__ void k_copyblk(const double* __restrict__ S, int lds,
                          double* __restrict__ Dst, int ldd, int total, int cols) {
  int idx = blockIdx.x * 256 + threadIdx.x;
  if (idx < total) {
    int r = idx / cols, c = idx % cols;
    Dst[r * ldd + c] = S[r * lds + c];
  }
}

// Mstack (448x320 fp32): rows 0..127  = sc_i*[-H21 | D12]   (base matrix, prescaled)
//                        rows 128..447 = [A_x|A_u ; G_x|G_u] (x/u part of output matrix)
__global__ void k_pack_mstack(const double* __restrict__ H, const float* __restrict__ D12,
                              const double* __restrict__ sc, const double* __restrict__ Axwu,
                              const double* __restrict__ G, float* __restrict__ Ms) {
  int idx = blockIdx.x * 256 + threadIdx.x;  // 448*320
  int rr = idx / 320, k = idx % 320;
  double v;
  if (rr < 128) {
    double s = sc[rr];
    v = (k < 256) ? (-H[(256 + rr) * NTWO + k] * s)
                  : ((double)D12[rr * DINN + (k - 256)] * s);
  } else {
    int r = rr - 128;
    const double* src = (r < 256) ? (Axwu + (size_t)r * 448) : (G + (size_t)(r - 256) * 448);
    v = (k < 256) ? src[k] : src[384 + (k - 256)];
  }
  Ms[idx] = (float)v;
}

// OmW (320x128 fp32): w-columns of [Axwu; G]
__global__ void k_pack_omw(const double* __restrict__ Axwu, const double* __restrict__ G,
                           float* __restrict__ OmW) {
  int idx = blockIdx.x * 256 + threadIdx.x;  // 320*128
  int r = idx >> 7, j = idx & 127;
  double v = (r < 256) ? Axwu[(size_t)r * 448 + 256 + j] : G[(size_t)(r - 256) * 448 + 256 + j];
  OmW[idx] = (float)v;
}

// Tp[j][c] = sc_c * D11[c][j] = -sc_c*H22[c][j] for c>j else 0   (column-major scaled D11)
__global__ void k_pack_tp(const double* __restrict__ H, const double* __restrict__ sc,
                          float* __restrict__ Tp) {
  int idx = blockIdx.x * 256 + threadIdx.x;  // 128*128
  int j = idx >> 7, c = idx & 127;
  double v = (c > j) ? (-H[(256 + c) * NTWO + 256 + j] * sc[c]) : 0.0;
  Tp[idx] = (float)v;
}

// ---------------- main scan: 128 WGs x NB=4 batch, 511 steps ----------------
__global__ __launch_bounds__(256)
void k_scan(const float* __restrict__ u_in, const float* __restrict__ Ms,
            const float* __restrict__ OmW, const float* __restrict__ Tp,
            float* __restrict__ out) {
  __shared__ float xu[NB * 320];   // per-sample z = [x(256); u(64)]
  __shared__ float wv[NB * 128];
  __shared__ float acc[NB * 128];  // scaled pre-activations
  const int tid = threadIdx.x;
  const int b0 = blockIdx.x * NB;

  for (int i = tid; i < NB * 320; i += 256) xu[i] = 0.0f;
  {  // y(t=0) = 0
    int b = tid >> 6, o = tid & 63;
    out[(size_t)(b0 + b) * HORN * DOUTN + o] = 0.0f;
  }
  __syncthreads();

  const int r1 = tid;        // stacked rows 0..255
  const int r2 = 256 + tid;  // stacked rows 256..447 (valid if tid<192)
  const bool has2 = (tid < 192);
  const float* mr1 = Ms + (size_t)r1 * 320;
  const float* mr2 = Ms + (size_t)r2 * 320;
  const float* o1 = OmW + (size_t)((r1 >= 128) ? (r1 - 128) : 0) * 128;
  const float* o2 = OmW + (size_t)(r2 - 128) * 128;

  for (int t = 0; t < HORN - 1; ++t) {
    {  // load u_t
      int b = tid >> 6, c = tid & 63;
      xu[b * 320 + 256 + c] =
          u_in[(size_t)(b0 + b) * HORN * DINN + (size_t)t * DINN + c];
    }
    __syncthreads();

    // Phase A: stacked GEMV over z=[x;u]; rows<128 -> scaled base, rows>=128 -> out(x,u) part
    float a1[NB] = {0.f, 0.f, 0.f, 0.f};
    float a2[NB] = {0.f, 0.f, 0.f, 0.f};
    for (int k = 0; k < 320; k += 4) {
      const float4 m1 = *(const float4*)(mr1 + k);
      float4 m2v = make_float4(0.f, 0.f, 0.f, 0.f);
      if (has2) m2v = *(const float4*)(mr2 + k);
#pragma unroll
      for (int b = 0; b < NB; ++b) {
        const float* z = xu + b * 320 + k;
        const float z0 = z[0], z1 = z[1], z2 = z[2], z3 = z[3];
        a1[b] += m1.x * z0 + m1.y * z1 + m1.z * z2 + m1.w * z3;
        a2[b] += m2v.x * z0 + m2v.y * z1 + m2v.z * z2 + m2v.w * z3;
      }
    }
    if (r1 < 128) {
#pragma unroll
      for (int b = 0; b < NB; ++b) acc[b * 128 + r1] = a1[b];
    }
    __syncthreads();

    // Chain: 8 blocks of 16 channels; tanh(v/Lam) == (2^a - 1)/(2^a + 1), a prescaled
    for (int B = 0; B < 8; ++B) {
      const int cb = B * 16;
      if (tid < NB) {
        const int b = tid;
        float a[16];
#pragma unroll
        for (int r = 0; r < 16; ++r) a[r] = acc[b * 128 + cb + r];
#pragma unroll
        for (int j = 0; j < 16; ++j) {
          const float s = exp2f(a[j]);
          const float w = (s - 1.0f) / (s + 1.0f);
          wv[b * 128 + cb + j] = w;
#pragma unroll
          for (int r = j + 1; r < 16; ++r)
            a[r] += Tp[(cb + j) * 128 + (cb + r)] * w;
        }
      }
      __syncthreads();
      if (B < 7) {  // far-field rank-16 update by all threads
        const int b = tid >> 6, lc = tid & 63;
        for (int c = cb + 16 + lc; c < 128; c += 64) {
          float f = acc[b * 128 + c];
#pragma unroll
          for (int j = 0; j < 16; ++j)
            f += Tp[(cb + j) * 128 + c] * wv[b * 128 + cb + j];
          acc[b * 128 + c] = f;
        }
        __syncthreads();
      }
    }

    // Phase C: add w-contribution for stacked rows >= 128
    if (r1 >= 128) {
      for (int k = 0; k < 128; k += 4) {
        const float4 m = *(const float4*)(o1 + k);
#pragma unroll
        for (int b = 0; b < NB; ++b) {
          const float* z = wv + b * 128 + k;
          a1[b] += m.x * z[0] + m.y * z[1] + m.z * z[2] + m.w * z[3];
        }
      }
    }
    if (has2) {
      for (int k = 0; k < 128; k += 4) {
        const float4 m = *(const float4*)(o2 + k);
#pragma unroll
        for (int b = 0; b < NB; ++b) {
          const float* z = wv + b * 128 + k;
          a2[b] += m.x * z[0] + m.y * z[1] + m.z * z[2] + m.w * z[3];
        }
      }
    }

    // writeback: stacked rows 128..383 -> new x, 384..447 -> y(t+1)
    if (r1 >= 128) {
      const int r = r1 - 128;  // x rows 0..127
#pragma unroll
      for (int b = 0; b < NB; ++b) xu[b * 320 + r] = a1[b];
    }
    if (has2) {
      const int r = r2 - 128;  // 128..319
      if (r < 256) {
#pragma unroll
        for (int b = 0; b < NB; ++b) xu[b * 320 + r] = a2[b];
      } else {
        const int o = r - 256;
#pragma unroll
        for (int b = 0; b < NB; ++b)
          out[(size_t)(b0 + b) * HORN * DOUTN + (size_t)(t + 1) * DOUTN + o] = a2[b];
      }
    }
    __syncthreads();
  }
}

// ---------------- host ----------------
extern "C" void kernel_launch(void* const* d_in, const int* in_sizes, int n_in,
                              void* d_out, int out_size, void* d_ws, size_t ws_size,
                              hipStream_t stream) {
  (void)in_sizes; (void)n_in; (void)out_size; (void)ws_size;
  const float* u_in = (const float*)d_in[0];
  const float* X    = (const float*)d_in[1];
  const float* Y    = (const float*)d_in[2];
  const float* B2   = (const float*)d_in[3];
  const float* C2   = (const float*)d_in[4];
  const float* D21  = (const float*)d_in[5];
  const float* D12  = (const float*)d_in[6];
  float* out = (float*)d_out;

  double* H    = (double*)d_ws;            // 640*640
  double* E    = H + 640 * 640;            // 256*256
  double* Ai   = E + 256 * 256;            // 128*128
  double* CMm  = Ai + 128 * 128;
  double* MBm  = CMm + 128 * 128;
  double* Sm   = MBm + 128 * 128;
  double* Tm   = Sm + 128 * 128;
  double* Einv = Tm + 128 * 128;           // 256*256
  double* Axwu = Einv + 256 * 256;         // 256*448
  double* G    = Axwu + 256 * 448;         // 64*448
  double* B2d  = G + 64 * 448;             // 256*64
  double* C2d  = B2d + 256 * 64;           // 64*256
  double* Dxt  = C2d + 64 * 256;           // 64*448
  double* Eye2 = Dxt + 64 * 448;           // 128*128
  double* M0d  = Eye2 + 128 * 128;
  double* M1d  = M0d + 128 * 128;
  double* Rb   = M1d + 128 * 128;
  double* scv  = Rb + 128 * 128;           // 128
  float*  F32  = (float*)(scv + 128);      // 128*128
  float*  Ms   = F32 + 128 * 128;          // 448*320
  float*  OmW  = Ms + 448 * 320;           // 320*128
  float*  Tp   = OmW + 320 * 128;          // 128*128

  dim3 blk16(16, 16);
  k_xtx<<<dim3(40, 40), blk16, 0, stream>>>(X, H);
  k_build_e<<<256, 256, 0, stream>>>(H, Y, E);
  k_sc<<<1, 128, 0, stream>>>(H, scv);
  k_cast_f2d<<<64, 256, 0, stream>>>(B2, B2d, 256 * 64);
  k_cast_f2d<<<64, 256, 0, stream>>>(C2, C2d, 64 * 256);
  k_dext<<<112, 256, 0, stream>>>(D21, Dxt);
  k_eye2<<<64, 256, 0, stream>>>(Eye2);

  auto inv128 = [&](const double* A, int lda, double* Out) {
    k_ginv32<<<1, 256, 0, stream>>>(A, lda, F32);
    k_cast_f2d<<<64, 256, 0, stream>>>(F32, M0d, 128 * 128);
    // two Newton-Schulz refinements: M <- M(2I - A M)
    k_dgemm<<<dim3(8, 8), blk16, 0, stream>>>(128, 128, 128, A, lda, M0d, 128, -1.0, Eye2, 128, 1.0, Rb, 128);
    k_dgemm<<<dim3(8, 8), blk16, 0, stream>>>(128, 128, 128, M0d, 128, Rb, 128, 1.0, (const double*)nullptr, 0, 0.0, M1d, 128);
    k_dgemm<<<dim3(8, 8), blk16, 0, stream>>>(128, 128, 128, A, lda, M1d, 128, -1.0, Eye2, 128, 1.0, Rb, 128);
    k_dgemm<<<dim3(8, 8), blk16, 0, stream>>>(128, 128, 128, M1d, 128, Rb, 128, 1.0, (const double*)nullptr, 0, 0.0, Out, 128);
  };

  const double* EA = E;
  const double* EB = E + 128;
  const double* EC = E + 128 * 256;
  const double* ED = E + 128 * 256 + 128;

  // Schur-complement inversion of E (256x256)
  inv128(EA, 256, Ai);
  k_dgemm<<<dim3(8, 8), blk16, 0, stream>>>(128, 128, 128, EC, 256, Ai, 128, 1.0, (const double*)nullptr, 0, 0.0, CMm, 128);
  k_dgemm<<<dim3(8, 8), blk16, 0, stream>>>(128, 128, 128, Ai, 128, EB, 256, 1.0, (const double*)nullptr, 0, 0.0, MBm, 128);
  k_dgemm<<<dim3(8, 8), blk16, 0, stream>>>(128, 128, 128, CMm, 128, EB, 256, -1.0, ED, 256, 1.0, Sm, 128);
  inv128(Sm, 128, Tm);
  k_dgemm<<<dim3(8, 8), blk16, 0, stream>>>(128, 128, 128, Tm, 128, CMm, 128, -1.0, (const double*)nullptr, 0, 0.0, Einv + 128 * 256, 256);
  k_dgemm<<<dim3(8, 8), blk16, 0, stream>>>(128, 128, 128, MBm, 128, Tm, 128, -1.0, (const double*)nullptr, 0, 0.0, Einv + 128, 256);
  k_dgemm<<<dim3(8, 8), blk16, 0, stream>>>(128, 128, 128, MBm, 128, Einv + 128 * 256, 256, -1.0, Ai, 128, 1.0, Einv, 256);
  k_copyblk<<<64, 256, 0, stream>>>(Tm, 128, Einv + 128 * 256 + 128, 256, 128 * 128, 128);

  // Axwu = Einv @ [Fm | B1 | B2]   ([Fm|B1] is contiguous in H rows 384..639)
  k_dgemm<<<dim3(24, 16), blk16, 0, stream>>>(256, 384, 256, Einv, 256, H + 384 * NTWO, NTWO, 1.0, (const double*)nullptr, 0, 0.0, Axwu, 448);
  k_dgemm<<<dim3(4, 16), blk16, 0, stream>>>(256, 64, 256, Einv, 256, B2d, 64, 1.0, (const double*)nullptr, 0, 0.0, Axwu + 384, 448);
  // G = C2 @ Axwu + [0 | D21 | 0]
  k_dgemm<<<dim3(28, 4), blk16, 0, stream>>>(64, 448, 256, C2d, 256, Axwu, 448, 1.0, Dxt, 448, 1.0, G, 448);

  k_pack_mstack<<<560, 256, 0, stream>>>(H, D12, scv, Axwu, G, Ms);
  k_pack_omw<<<160, 256, 0, stream>>>(Axwu, G, OmW);
  k_pack_tp<<<64, 256, 0, stream>>>(H, scv, Tp);

  k_scan<<<BATCHN / NB, 256, 0, stream>>>(u_in, Ms, OmW, Tp, out);
}

// Round 2
// 11987.460 us; speedup vs baseline: 2.1770x; 2.1770x over previous
//
#include <hip/hip_runtime.h>
#include <math.h>
#include <stddef.h>

#define NTWO 640
#define DXN 256
#define DNLN 128
#define DINN 64
#define DOUTN 64
#define BATCHN 512
#define HORN 512
#define EPSV 1.0e-3

typedef unsigned int uint;
typedef unsigned short ushort;
typedef _Float16 half2_t __attribute__((ext_vector_type(2)));

__device__ __forceinline__ float fdot2(uint a, uint b, float c) {
#if __has_builtin(__builtin_amdgcn_fdot2)
  return __builtin_amdgcn_fdot2(__builtin_bit_cast(half2_t, a),
                                __builtin_bit_cast(half2_t, b), c, false);
#else
  half2_t x = __builtin_bit_cast(half2_t, a), y = __builtin_bit_cast(half2_t, b);
  return c + (float)x[0] * (float)y[0] + (float)x[1] * (float)y[1];
#endif
}

__device__ __forceinline__ uint pack_f16(float x, float y) {
  _Float16 hx = (_Float16)x, hy = (_Float16)y;
  ushort ux = __builtin_bit_cast(ushort, hx), uy = __builtin_bit_cast(ushort, hy);
  return ((uint)uy << 16) | (uint)ux;
}

__device__ __forceinline__ float fast_exp2(float x) {
#if __has_builtin(__builtin_amdgcn_exp2f)
  return __builtin_amdgcn_exp2f(x);
#else
  return exp2f(x);
#endif
}

__device__ __forceinline__ float bcast_lane(float v, int l) {
#if __has_builtin(__builtin_amdgcn_readlane)
  return __builtin_bit_cast(float, __builtin_amdgcn_readlane(__builtin_bit_cast(int, v), l));
#else
  return __shfl(v, l, 64);
#endif
}

// ---------------- precompute kernels (one-time, f64) ----------------

__global__ void k_xtx(const float* __restrict__ X, double* __restrict__ H) {
  __shared__ float sA[16][17];
  __shared__ float sB[16][17];
  const int tx = threadIdx.x, ty = threadIdx.y;
  const int bi = blockIdx.y * 16, bj = blockIdx.x * 16;
  double acc = 0.0;
  for (int k0 = 0; k0 < NTWO; k0 += 16) {
    sA[ty][tx] = X[(k0 + ty) * NTWO + bi + tx];
    sB[ty][tx] = X[(k0 + ty) * NTWO + bj + tx];
    __syncthreads();
#pragma unroll
    for (int kk = 0; kk < 16; ++kk)
      acc += (double)sA[kk][ty] * (double)sB[kk][tx];
    __syncthreads();
  }
  const int i = bi + ty, j = bj + tx;
  if (i == j) acc += EPSV;
  H[i * NTWO + j] = acc;
}

__global__ void k_build_e(const double* __restrict__ H, const float* __restrict__ Y,
                          double* __restrict__ E) {
  int idx = blockIdx.x * 256 + threadIdx.x;
  int i = idx >> 8, j = idx & 255;
  E[idx] = 0.5 * (H[i * NTWO + j] + H[(384 + i) * NTWO + 384 + j]
                  + (double)Y[i * 256 + j] - (double)Y[j * 256 + i]);
}

__global__ void k_sc(const double* __restrict__ H, double* __restrict__ sc) {
  int i = threadIdx.x;
  if (i < 128) {
    double lam = 0.5 * H[(256 + i) * NTWO + 256 + i];
    sc[i] = 2.8853900817779268 / lam;
  }
}

__global__ void k_cast_f2d(const float* __restrict__ s, double* __restrict__ d, int n) {
  int i = blockIdx.x * 256 + threadIdx.x;
  if (i < n) d[i] = (double)s[i];
}

__global__ void k_eye2(double* __restrict__ A) {
  int idx = blockIdx.x * 256 + threadIdx.x;
  int r = idx >> 7, c = idx & 127;
  A[idx] = (r == c) ? 2.0 : 0.0;
}

__global__ void k_dext(const float* __restrict__ D21, double* __restrict__ Dx) {
  int idx = blockIdx.x * 256 + threadIdx.x;  // 64*448
  int r = idx / 448, c = idx % 448;
  double v = 0.0;
  if (c >= 256 && c < 384) v = (double)D21[r * 128 + (c - 256)];
  Dx[idx] = v;
}

__global__ void k_ginv32(const double* __restrict__ A, int lda, float* __restrict__ Out) {
  __shared__ float M[128 * 128];
  const int tid = threadIdx.x;
  for (int i = tid; i < 128 * 128; i += 256)
    M[i] = (float)A[(i >> 7) * lda + (i & 127)];
  __syncthreads();
  for (int k = 0; k < 128; ++k) {
    float ip = 1.0f / M[k * 128 + k];
    __syncthreads();
    if (tid < 128) {
      float v = M[k * 128 + tid];
      M[k * 128 + tid] = (tid == k) ? ip : v * ip;
    }
    __syncthreads();
    const int i0 = tid >> 1, half = tid & 1;
    float f = (i0 != k) ? M[i0 * 128 + k] : 0.0f;
    __syncthreads();
    if (i0 != k) {
      const float* rk = M + k * 128;
      float* ri = M + i0 * 128;
      const int j0 = half * 64;
#pragma unroll 8
      for (int j = j0; j < j0 + 64; ++j) {
        float v = (j == k) ? 0.0f : ri[j];
        ri[j] = v - f * rk[j];
      }
    }
    __syncthreads();
  }
  for (int i = tid; i < 128 * 128; i += 256) Out[i] = M[i];
}

__global__ void k_dgemm(int M, int N, int K,
                        const double* __restrict__ A, int lda,
                        const double* __restrict__ B, int ldb,
                        double alpha,
                        const double* __restrict__ D, int ldd, double beta,
                        double* __restrict__ C, int ldc) {
  __shared__ double sA[16][17];
  __shared__ double sB[16][17];
  const int tx = threadIdx.x, ty = threadIdx.y;
  const int row = blockIdx.y * 16 + ty, col = blockIdx.x * 16 + tx;
  double acc = 0.0;
  for (int k0 = 0; k0 < K; k0 += 16) {
    sA[ty][tx] = A[row * lda + k0 + tx];
    sB[ty][tx] = B[(k0 + ty) * ldb + col];
    __syncthreads();
#pragma unroll
    for (int kk = 0; kk < 16; ++kk) acc += sA[ty][kk] * sB[kk][tx];
    __syncthreads();
  }
  double v = alpha * acc;
  if (beta != 0.0) v += beta * D[row * ldd + col];
  C[row * ldc + col] = v;
}

__global__ void k_copyblk(const double* __restrict__ S, int lds,
                          double* __restrict__ Dst, int ldd, int total, int cols) {
  int idx = blockIdx.x * 256 + threadIdx.x;
  if (idx < total) {
    int r = idx / cols, c = idx % cols;
    Dst[r * ldd + c] = S[r * lds + c];
  }
}

// Msh: 448x320 f16, packed as uint dwords (2 cols), k-major layout:
// dword d of row rr stored at Msh[((d>>2)*448 + rr)*4 + (d&3)]
__global__ void k_pack_msh(const double* __restrict__ H, const float* __restrict__ D12,
                           const double* __restrict__ sc, const double* __restrict__ Axwu,
                           const double* __restrict__ G, uint* __restrict__ Msh) {
  int idx = blockIdx.x * 256 + threadIdx.x;  // 448*160
  if (idx >= 448 * 160) return;
  int rr = idx / 160, d = idx % 160;
  float v[2];
#pragma unroll
  for (int e = 0; e < 2; ++e) {
    int k = 2 * d + e;
    double x;
    if (rr < 128) {
      double s = sc[rr];
      x = (k < 256) ? (-H[(256 + rr) * NTWO + k] * s)
                    : ((double)D12[rr * DINN + (k - 256)] * s);
    } else {
      int r2 = rr - 128;
      const double* src = (r2 < 256) ? (Axwu + (size_t)r2 * 448) : (G + (size_t)(r2 - 256) * 448);
      x = (k < 256) ? src[k] : src[384 + (k - 256)];
    }
    v[e] = (float)x;
  }
  Msh[((size_t)(d >> 2) * 448 + rr) * 4 + (d & 3)] = pack_f16(v[0], v[1]);
}

// OmWh: 320x128 f16 (w-columns of [Axwu;G]), k-major dword layout over 320 rows
__global__ void k_pack_omwh(const double* __restrict__ Axwu, const double* __restrict__ G,
                            uint* __restrict__ OmWh) {
  int idx = blockIdx.x * 256 + threadIdx.x;  // 320*64
  if (idx >= 320 * 64) return;
  int rr = idx / 64, d = idx % 64;
  float v[2];
#pragma unroll
  for (int e = 0; e < 2; ++e) {
    int j = 2 * d + e;
    double x = (rr < 256) ? Axwu[(size_t)rr * 448 + 256 + j]
                          : G[(size_t)(rr - 256) * 448 + 256 + j];
    v[e] = (float)x;
  }
  OmWh[((size_t)(d >> 2) * 320 + rr) * 4 + (d & 3)] = pack_f16(v[0], v[1]);
}

// TpP: strictly-lower triangle of (sc_c * D11[c][j]) packed column-major:
// col j holds entries c=j+1..127 at base 127*j - j*(j-1)/2
__global__ void k_pack_tpp(const double* __restrict__ H, const double* __restrict__ sc,
                           float* __restrict__ TpP) {
  int idx = blockIdx.x * 256 + threadIdx.x;  // 128*128
  int j = idx >> 7, c = idx & 127;
  if (c > j) {
    int pidx = 127 * j - (j * (j - 1)) / 2 + (c - j - 1);
    TpP[pidx] = (float)(-H[(256 + c) * NTWO + 256 + j] * sc[c]);
  }
}

// ---------------- main scan: 256 WGs x 512 threads, NB=2 ----------------
__global__ __launch_bounds__(512, 2)
void k_scan(const float* __restrict__ u_in, const uint* __restrict__ Msh,
            const uint* __restrict__ OmWh, const float* __restrict__ TpP,
            float* __restrict__ out) {
  __shared__ float accL[2 * 128];
  __shared__ float wvL[2 * 128];
  __shared__ uint __align__(16) wvhL[2 * 64];
  __shared__ uint __align__(16) xuhL[2 * 160];
  __shared__ float TpL[8128];
  const int tid = threadIdx.x;
  const int bb = blockIdx.x * 2;

  for (int i = tid; i < 8128; i += 512) TpL[i] = TpP[i];
  if (tid < 256) { int b = tid >> 7, k = tid & 127; xuhL[b * 160 + k] = 0u; }
  if (tid < 128) {
    int b = tid >> 6, o = tid & 63;
    out[((size_t)(bb + b) * HORN) * DOUTN + o] = 0.0f;
  }
  if (tid >= 448) {
    int l = tid - 448, b = l >> 5, k = l & 31;
    const float* up = u_in + ((size_t)(bb + b) * HORN) * DINN + 2 * k;
    xuhL[b * 160 + 128 + k] = pack_f16(up[0], up[1]);
  }
  __syncthreads();

  const int r = tid;
  float unx = 0.f, uny = 0.f;

  for (int t = 0; t < HORN - 1; ++t) {
    float a0 = 0.f, a1 = 0.f;
    if (r < 448) {
      const uint4* __restrict__ mp = (const uint4*)Msh;
      const uint4* z0 = (const uint4*)(xuhL);
      const uint4* z1 = (const uint4*)(xuhL + 160);
#pragma unroll 4
      for (int i = 0; i < 40; ++i) {
        uint4 m = mp[(size_t)i * 448 + r];
        uint4 p = z0[i], q = z1[i];
        a0 = fdot2(m.x, p.x, a0); a0 = fdot2(m.y, p.y, a0);
        a0 = fdot2(m.z, p.z, a0); a0 = fdot2(m.w, p.w, a0);
        a1 = fdot2(m.x, q.x, a1); a1 = fdot2(m.y, q.y, a1);
        a1 = fdot2(m.z, q.z, a1); a1 = fdot2(m.w, q.w, a1);
      }
      if (r < 128) { accL[r] = a0; accL[128 + r] = a1; }
    } else {
      // wave 7: prefetch u_{t+1}
      int l = tid - 448, b = l >> 5, k = l & 31;
      const float* up = u_in + ((size_t)(bb + b) * HORN + (t + 1)) * DINN + 2 * k;
      unx = up[0]; uny = up[1];
    }
    __syncthreads();  // B1: acc ready

    if (tid < 128) {
      const int b = tid >> 6, lane = tid & 63;
      float c0 = accL[b * 128 + lane];
      float c1 = accL[b * 128 + 64 + lane];
      int pj = 0;
      for (int j = 0; j < 64; ++j) {
        float av = bcast_lane(c0, j);
        float s = fast_exp2(av);
        float w = (s - 1.0f) * __builtin_amdgcn_rcpf(s + 1.0f);
        if (lane == j) wvL[b * 128 + j] = w;
        float tv0 = TpL[pj + ((lane > j) ? (lane - j - 1) : 0)];
        c0 += ((lane > j) ? tv0 : 0.0f) * w;
        c1 += TpL[pj + (lane + 63 - j)] * w;  // c=lane+64 > j always
        pj += 127 - j;
      }
      for (int j = 64; j < 128; ++j) {
        float av = bcast_lane(c1, j - 64);
        float s = fast_exp2(av);
        float w = (s - 1.0f) * __builtin_amdgcn_rcpf(s + 1.0f);
        if (lane == j - 64) wvL[b * 128 + j] = w;
        int off = lane + 63 - j;  // (lane+64)-1-j
        float tv = TpL[pj + ((off >= 0) ? off : 0)];
        c1 += ((off >= 0) ? tv : 0.0f) * w;
        pj += 127 - j;
      }
      // pack w -> f16 dwords (wave-local; wv fully written by this wave)
      float w0 = wvL[b * 128 + 2 * lane], w1 = wvL[b * 128 + 2 * lane + 1];
      wvhL[b * 64 + lane] = pack_f16(w0, w1);
    } else if (tid >= 448) {
      int l = tid - 448, b = l >> 5, k = l & 31;
      xuhL[b * 160 + 128 + k] = pack_f16(unx, uny);
    }
    __syncthreads();  // B2: wvh + next-u ready

    if (r >= 128 && r < 448) {
      const uint4* wp0 = (const uint4*)(wvhL);
      const uint4* wp1 = (const uint4*)(wvhL + 64);
      const uint4* op = (const uint4*)OmWh;
      const int rr = r - 128;  // 0..319
#pragma unroll 4
      for (int i = 0; i < 16; ++i) {
        uint4 m = op[(size_t)i * 320 + rr];
        uint4 p = wp0[i], q = wp1[i];
        a0 = fdot2(m.x, p.x, a0); a0 = fdot2(m.y, p.y, a0);
        a0 = fdot2(m.z, p.z, a0); a0 = fdot2(m.w, p.w, a0);
        a1 = fdot2(m.x, q.x, a1); a1 = fdot2(m.y, q.y, a1);
        a1 = fdot2(m.z, q.z, a1); a1 = fdot2(m.w, q.w, a1);
      }
      if (r < 384) {
        // x rows 0..255: pack pairs (even lane takes odd neighbor's value)
        float n0 = __shfl_down(a0, 1, 64);
        float n1 = __shfl_down(a1, 1, 64);
        if ((rr & 1) == 0) {
          xuhL[0 * 160 + (rr >> 1)] = pack_f16(a0, n0);
          xuhL[1 * 160 + (rr >> 1)] = pack_f16(a1, n1);
        }
      } else {
        const int o = r - 384;
        size_t base = ((size_t)bb * HORN + (t + 1)) * DOUTN + o;
        out[base] = a0;
        out[base + (size_t)HORN * DOUTN] = a1;
      }
    }
    __syncthreads();  // B3: xuh ready for next step
  }
}

// ---------------- host ----------------
extern "C" void kernel_launch(void* const* d_in, const int* in_sizes, int n_in,
                              void* d_out, int out_size, void* d_ws, size_t ws_size,
                              hipStream_t stream) {
  (void)in_sizes; (void)n_in; (void)out_size; (void)ws_size;
  const float* u_in = (const float*)d_in[0];
  const float* X    = (const float*)d_in[1];
  const float* Y    = (const float*)d_in[2];
  const float* B2   = (const float*)d_in[3];
  const float* C2   = (const float*)d_in[4];
  const float* D21  = (const float*)d_in[5];
  const float* D12  = (const float*)d_in[6];
  float* out = (float*)d_out;

  double* H    = (double*)d_ws;            // 640*640
  double* E    = H + 640 * 640;            // 256*256
  double* Ai   = E + 256 * 256;            // 128*128
  double* CMm  = Ai + 128 * 128;
  double* MBm  = CMm + 128 * 128;
  double* Sm   = MBm + 128 * 128;
  double* Tm   = Sm + 128 * 128;
  double* Einv = Tm + 128 * 128;           // 256*256
  double* Axwu = Einv + 256 * 256;         // 256*448
  double* G    = Axwu + 256 * 448;         // 64*448
  double* B2d  = G + 64 * 448;             // 256*64
  double* C2d  = B2d + 256 * 64;           // 64*256
  double* Dxt  = C2d + 64 * 256;           // 64*448
  double* Eye2 = Dxt + 64 * 448;           // 128*128
  double* M0d  = Eye2 + 128 * 128;
  double* Rb   = M0d + 128 * 128;
  double* scv  = Rb + 128 * 128;           // 128
  float*  F32  = (float*)(scv + 128);      // 128*128
  uint*   Msh  = (uint*)(F32 + 128 * 128); // 71680
  uint*   OmWh = Msh + 71680;              // 20480
  float*  TpP  = (float*)(OmWh + 20480);   // 8128

  dim3 blk16(16, 16);
  k_xtx<<<dim3(40, 40), blk16, 0, stream>>>(X, H);
  k_build_e<<<256, 256, 0, stream>>>(H, Y, E);
  k_sc<<<1, 128, 0, stream>>>(H, scv);
  k_cast_f2d<<<64, 256, 0, stream>>>(B2, B2d, 256 * 64);
  k_cast_f2d<<<64, 256, 0, stream>>>(C2, C2d, 64 * 256);
  k_dext<<<112, 256, 0, stream>>>(D21, Dxt);
  k_eye2<<<64, 256, 0, stream>>>(Eye2);

  auto inv128 = [&](const double* A, int lda, double* Out) {
    k_ginv32<<<1, 256, 0, stream>>>(A, lda, F32);
    k_cast_f2d<<<64, 256, 0, stream>>>(F32, M0d, 128 * 128);
    // one Newton-Schuls refinement: M <- M0(2I - A M0)
    k_dgemm<<<dim3(8, 8), blk16, 0, stream>>>(128, 128, 128, A, lda, M0d, 128, -1.0, Eye2, 128, 1.0, Rb, 128);
    k_dgemm<<<dim3(8, 8), blk16, 0, stream>>>(128, 128, 128, M0d, 128, Rb, 128, 1.0, (const double*)nullptr, 0, 0.0, Out, 128);
  };

  const double* EA = E;
  const double* EB = E + 128;
  const double* EC = E + 128 * 256;
  const double* ED = E + 128 * 256 + 128;

  inv128(EA, 256, Ai);
  k_dgemm<<<dim3(8, 8), blk16, 0, stream>>>(128, 128, 128, EC, 256, Ai, 128, 1.0, (const double*)nullptr, 0, 0.0, CMm, 128);
  k_dgemm<<<dim3(8, 8), blk16, 0, stream>>>(128, 128, 128, Ai, 128, EB, 256, 1.0, (const double*)nullptr, 0, 0.0, MBm, 128);
  k_dgemm<<<dim3(8, 8), blk16, 0, stream>>>(128, 128, 128, CMm, 128, EB, 256, -1.0, ED, 256, 1.0, Sm, 128);
  inv128(Sm, 128, Tm);
  k_dgemm<<<dim3(8, 8), blk16, 0, stream>>>(128, 128, 128, Tm, 128, CMm, 128, -1.0, (const double*)nullptr, 0, 0.0, Einv + 128 * 256, 256);
  k_dgemm<<<dim3(8, 8), blk16, 0, stream>>>(128, 128, 128, MBm, 128, Tm, 128, -1.0, (const double*)nullptr, 0, 0.0, Einv + 128, 256);
  k_dgemm<<<dim3(8, 8), blk16, 0, stream>>>(128, 128, 128, MBm, 128, Einv + 128 * 256, 256, -1.0, Ai, 128, 1.0, Einv, 256);
  k_copyblk<<<64, 256, 0, stream>>>(Tm, 128, Einv + 128 * 256 + 128, 256, 128 * 128, 128);

  // Axwu = Einv @ [Fm | B1 | B2]
  k_dgemm<<<dim3(24, 16), blk16, 0, stream>>>(256, 384, 256, Einv, 256, H + 384 * NTWO, NTWO, 1.0, (const double*)nullptr, 0, 0.0, Axwu, 448);
  k_dgemm<<<dim3(4, 16), blk16, 0, stream>>>(256, 64, 256, Einv, 256, B2d, 64, 1.0, (const double*)nullptr, 0, 0.0, Axwu + 384, 448);
  // G = C2 @ Axwu + [0 | D21 | 0]
  k_dgemm<<<dim3(28, 4), blk16, 0, stream>>>(64, 448, 256, C2d, 256, Axwu, 448, 1.0, Dxt, 448, 1.0, G, 448);

  k_pack_msh<<<280, 256, 0, stream>>>(H, D12, scv, Axwu, G, Msh);
  k_pack_omwh<<<80, 256, 0, stream>>>(Axwu, G, OmWh);
  k_pack_tpp<<<64, 256, 0, stream>>>(H, scv, TpP);

  k_scan<<<BATCHN / 2, 512, 0, stream>>>(u_in, Msh, OmWh, TpP, out);
}

// Round 3
// 8623.796 us; speedup vs baseline: 3.0261x; 1.3900x over previous
//
#include <hip/hip_runtime.h>
#include <math.h>
#include <stddef.h>

#define NTWO 640
#define DXN 256
#define DNLN 128
#define DINN 64
#define DOUTN 64
#define BATCHN 512
#define HORN 512
#define EPSV 1.0e-3

typedef unsigned int uint;
typedef unsigned short ushort;
typedef _Float16 half2_t __attribute__((ext_vector_type(2)));

__device__ __forceinline__ float fdot2(uint a, uint b, float c) {
#if __has_builtin(__builtin_amdgcn_fdot2)
  return __builtin_amdgcn_fdot2(__builtin_bit_cast(half2_t, a),
                                __builtin_bit_cast(half2_t, b), c, false);
#else
  half2_t x = __builtin_bit_cast(half2_t, a), y = __builtin_bit_cast(half2_t, b);
  return c + (float)x[0] * (float)y[0] + (float)x[1] * (float)y[1];
#endif
}

__device__ __forceinline__ uint pack_f16(float x, float y) {
  _Float16 hx = (_Float16)x, hy = (_Float16)y;
  ushort ux = __builtin_bit_cast(ushort, hx), uy = __builtin_bit_cast(ushort, hy);
  return ((uint)uy << 16) | (uint)ux;
}

__device__ __forceinline__ float fast_exp2(float x) {
#if __has_builtin(__builtin_amdgcn_exp2f)
  return __builtin_amdgcn_exp2f(x);
#else
  return exp2f(x);
#endif
}

__device__ __forceinline__ float bcast_lane(float v, int l) {
#if __has_builtin(__builtin_amdgcn_readlane)
  return __builtin_bit_cast(float, __builtin_amdgcn_readlane(__builtin_bit_cast(int, v), l));
#else
  return __shfl(v, l, 64);
#endif
}

// ---------------- precompute kernels (one-time, f64) ----------------

__global__ void k_xtx(const float* __restrict__ X, double* __restrict__ H) {
  __shared__ float sA[16][17];
  __shared__ float sB[16][17];
  const int tx = threadIdx.x, ty = threadIdx.y;
  const int bi = blockIdx.y * 16, bj = blockIdx.x * 16;
  double acc = 0.0;
  for (int k0 = 0; k0 < NTWO; k0 += 16) {
    sA[ty][tx] = X[(k0 + ty) * NTWO + bi + tx];
    sB[ty][tx] = X[(k0 + ty) * NTWO + bj + tx];
    __syncthreads();
#pragma unroll
    for (int kk = 0; kk < 16; ++kk)
      acc += (double)sA[kk][ty] * (double)sB[kk][tx];
    __syncthreads();
  }
  const int i = bi + ty, j = bj + tx;
  if (i == j) acc += EPSV;
  H[i * NTWO + j] = acc;
}

// fused small prep: E, sc, B2 cast, C2 cast, Dxt, Eye2
__global__ void k_prep(const double* __restrict__ H, const float* __restrict__ Y,
                       const float* __restrict__ B2, const float* __restrict__ C2,
                       const float* __restrict__ D21,
                       double* __restrict__ E, double* __restrict__ scv,
                       double* __restrict__ B2d, double* __restrict__ C2d,
                       double* __restrict__ Dxt, double* __restrict__ Eye2) {
  int idx = blockIdx.x * 256 + threadIdx.x;
  if (idx < 65536) {
    int i = idx >> 8, j = idx & 255;
    E[idx] = 0.5 * (H[i * NTWO + j] + H[(384 + i) * NTWO + 384 + j]
                    + (double)Y[i * 256 + j] - (double)Y[j * 256 + i]);
    return;
  }
  idx -= 65536;
  if (idx < 128) {
    double lam = 0.5 * H[(256 + idx) * NTWO + 256 + idx];
    scv[idx] = 2.8853900817779268 / lam;
    return;
  }
  idx -= 128;
  if (idx < 16384) { B2d[idx] = (double)B2[idx]; return; }
  idx -= 16384;
  if (idx < 16384) { C2d[idx] = (double)C2[idx]; return; }
  idx -= 16384;
  if (idx < 28672) {
    int r = idx / 448, c = idx % 448;
    double v = 0.0;
    if (c >= 256 && c < 384) v = (double)D21[r * 128 + (c - 256)];
    Dxt[idx] = v;
    return;
  }
  idx -= 28672;
  if (idx < 16384) {
    int r = idx >> 7, c = idx & 127;
    Eye2[idx] = (r == c) ? 2.0 : 0.0;
  }
}

// fp32 Gauss-Jordan inverse of 128x128 (no pivot; symmetric-part-PD input).
// LDS padded to 129 cols: column accesses spread across banks.
__global__ void k_ginv32(const double* __restrict__ A, int lda, float* __restrict__ Out) {
  __shared__ float M[128 * 129];
  const int tid = threadIdx.x;
  for (int i = tid; i < 128 * 128; i += 256)
    M[(i >> 7) * 129 + (i & 127)] = (float)A[(i >> 7) * lda + (i & 127)];
  __syncthreads();
  for (int k = 0; k < 128; ++k) {
    float ip = 1.0f / M[k * 129 + k];
    __syncthreads();
    if (tid < 128) {
      float v = M[k * 129 + tid];
      M[k * 129 + tid] = (tid == k) ? ip : v * ip;
    }
    __syncthreads();
    const int i0 = tid >> 1, half = tid & 1;
    float f = (i0 != k) ? M[i0 * 129 + k] : 0.0f;
    __syncthreads();
    if (i0 != k) {
      const float* rk = M + k * 129;
      float* ri = M + i0 * 129;
      const int j0 = half * 64;
#pragma unroll 8
      for (int j = j0; j < j0 + 64; ++j) {
        float v = (j == k) ? 0.0f : ri[j];
        ri[j] = v - f * rk[j];
      }
    }
    __syncthreads();
  }
  for (int i = tid; i < 128 * 128; i += 256) Out[i] = M[(i >> 7) * 129 + (i & 127)];
}

__global__ void k_dgemm(int M, int N, int K,
                        const double* __restrict__ A, int lda,
                        const double* __restrict__ B, int ldb,
                        double alpha,
                        const double* __restrict__ D, int ldd, double beta,
                        double* __restrict__ C, int ldc) {
  __shared__ double sA[16][17];
  __shared__ double sB[16][17];
  const int tx = threadIdx.x, ty = threadIdx.y;
  const int row = blockIdx.y * 16 + ty, col = blockIdx.x * 16 + tx;
  double acc = 0.0;
  for (int k0 = 0; k0 < K; k0 += 16) {
    sA[ty][tx] = A[row * lda + k0 + tx];
    sB[ty][tx] = B[(k0 + ty) * ldb + col];
    __syncthreads();
#pragma unroll
    for (int kk = 0; kk < 16; ++kk) acc += sA[ty][kk] * sB[kk][tx];
    __syncthreads();
  }
  double v = alpha * acc;
  if (beta != 0.0) v += beta * D[row * ldd + col];
  C[row * ldc + col] = v;
}

__global__ void k_copyblk(const double* __restrict__ S, int lds,
                          double* __restrict__ Dst, int ldd, int total, int cols) {
  int idx = blockIdx.x * 256 + threadIdx.x;
  if (idx < total) {
    int r = idx / cols, c = idx % cols;
    Dst[r * ldd + c] = S[r * lds + c];
  }
}

__global__ void k_cast_f2d(const float* __restrict__ s, double* __restrict__ d, int n) {
  int i = blockIdx.x * 256 + threadIdx.x;
  if (i < n) d[i] = (double)s[i];
}

// fused pack: Msh (448x320 f16, k-major dwords), OmWh (320x128 f16 k-major), TpP
__global__ void k_pack(const double* __restrict__ H, const float* __restrict__ D12,
                       const double* __restrict__ sc, const double* __restrict__ Axwu,
                       const double* __restrict__ G,
                       uint* __restrict__ Msh, uint* __restrict__ OmWh,
                       float* __restrict__ TpP) {
  int idx = blockIdx.x * 256 + threadIdx.x;
  if (idx < 448 * 160) {
    int rr = idx / 160, d = idx % 160;
    float v[2];
#pragma unroll
    for (int e = 0; e < 2; ++e) {
      int k = 2 * d + e;
      double x;
      if (rr < 128) {
        double s = sc[rr];
        x = (k < 256) ? (-H[(256 + rr) * NTWO + k] * s)
                      : ((double)D12[rr * DINN + (k - 256)] * s);
      } else {
        int r2 = rr - 128;
        const double* src = (r2 < 256) ? (Axwu + (size_t)r2 * 448) : (G + (size_t)(r2 - 256) * 448);
        x = (k < 256) ? src[k] : src[384 + (k - 256)];
      }
      v[e] = (float)x;
    }
    Msh[((size_t)(d >> 2) * 448 + rr) * 4 + (d & 3)] = pack_f16(v[0], v[1]);
    return;
  }
  idx -= 448 * 160;
  if (idx < 320 * 64) {
    int rr = idx / 64, d = idx % 64;
    float v[2];
#pragma unroll
    for (int e = 0; e < 2; ++e) {
      int j = 2 * d + e;
      double x = (rr < 256) ? Axwu[(size_t)rr * 448 + 256 + j]
                            : G[(size_t)(rr - 256) * 448 + 256 + j];
      v[e] = (float)x;
    }
    OmWh[((size_t)(d >> 2) * 320 + rr) * 4 + (d & 3)] = pack_f16(v[0], v[1]);
    return;
  }
  idx -= 320 * 64;
  if (idx < 16384) {
    int j = idx >> 7, c = idx & 127;
    if (c > j) {
      int pidx = 127 * j - (j * (j - 1)) / 2 + (c - j - 1);
      TpP[pidx] = (float)(-H[(256 + c) * NTWO + 256 + j] * sc[c]);
    }
  }
}

// ---------------- main scan: 256 WGs x 512 threads, NB=2 ----------------
// Msh rows live in per-thread registers; OmW in LDS (stride-65 dword rows);
// zero global loads inside the 511-step loop except u prefetch.
__global__ __launch_bounds__(512, 2)
void k_scan(const float* __restrict__ u_in, const uint* __restrict__ Msh,
            const uint* __restrict__ OmWh, const float* __restrict__ TpP,
            float* __restrict__ out) {
  __shared__ float accL[2 * 128];
  __shared__ float wvL[2 * 128];
  __shared__ uint __align__(16) wvhL[2 * 64];
  __shared__ uint __align__(16) xuhL[2 * 160];
  __shared__ float TpL[8128];
  __shared__ uint OmL[320 * 65];  // row rr at OmL[rr*65 .. rr*65+63]
  const int tid = threadIdx.x;
  const int bb = blockIdx.x * 2;

  for (int i = tid; i < 8128; i += 512) TpL[i] = TpP[i];
  for (int idx = tid; idx < 320 * 16; idx += 512) {
    const int i = idx / 320, rr = idx % 320;
    const uint4 v = ((const uint4*)OmWh)[(size_t)i * 320 + rr];
    uint* p = OmL + rr * 65 + i * 4;
    p[0] = v.x; p[1] = v.y; p[2] = v.z; p[3] = v.w;
  }
  if (tid < 256) { int b = tid >> 7, k = tid & 127; xuhL[b * 160 + k] = 0u; }
  if (tid < 128) {
    int b = tid >> 6, o = tid & 63;
    out[((size_t)(bb + b) * HORN) * DOUTN + o] = 0.0f;
  }
  if (tid >= 448) {
    int l = tid - 448, b = l >> 5, k = l & 31;
    const float* up = u_in + ((size_t)(bb + b) * HORN) * DINN + 2 * k;
    xuhL[b * 160 + 128 + k] = pack_f16(up[0], up[1]);
  }

  // load this thread's Msh row into registers (40 x uint4 = 160 VGPRs)
  uint4 mr[40];
  if (tid < 448) {
    const uint4* __restrict__ mp = (const uint4*)Msh;
#pragma unroll
    for (int i = 0; i < 40; ++i) mr[i] = mp[(size_t)i * 448 + tid];
  }
  __syncthreads();

  const int r = tid;
  float unx = 0.f, uny = 0.f;

  for (int t = 0; t < HORN - 1; ++t) {
    float a0 = 0.f, a1 = 0.f;
    if (r < 448) {
      const uint4* z0 = (const uint4*)(xuhL);
      const uint4* z1 = (const uint4*)(xuhL + 160);
#pragma unroll
      for (int i = 0; i < 40; ++i) {
        const uint4 m = mr[i];
        const uint4 p = z0[i], q = z1[i];
        a0 = fdot2(m.x, p.x, a0); a0 = fdot2(m.y, p.y, a0);
        a0 = fdot2(m.z, p.z, a0); a0 = fdot2(m.w, p.w, a0);
        a1 = fdot2(m.x, q.x, a1); a1 = fdot2(m.y, q.y, a1);
        a1 = fdot2(m.z, q.z, a1); a1 = fdot2(m.w, q.w, a1);
      }
      if (r < 128) { accL[r] = a0; accL[128 + r] = a1; }
    } else {
      // wave 7: prefetch u_{t+1}
      int l = tid - 448, b = l >> 5, k = l & 31;
      const float* up = u_in + ((size_t)(bb + b) * HORN + (t + 1)) * DINN + 2 * k;
      unx = up[0]; uny = up[1];
    }
    __syncthreads();  // B1: acc ready

    if (tid < 128) {
      const int b = tid >> 6, lane = tid & 63;
      float c0 = accL[b * 128 + lane];
      float c1 = accL[b * 128 + 64 + lane];
      int pj = 0;
      for (int j = 0; j < 64; ++j) {
        float av = bcast_lane(c0, j);
        float s = fast_exp2(av);
        float w = (s - 1.0f) * __builtin_amdgcn_rcpf(s + 1.0f);
        if (lane == j) wvL[b * 128 + j] = w;
        float tv0 = TpL[pj + ((lane > j) ? (lane - j - 1) : 0)];
        c0 += ((lane > j) ? tv0 : 0.0f) * w;
        c1 += TpL[pj + (lane + 63 - j)] * w;
        pj += 127 - j;
      }
      for (int j = 64; j < 128; ++j) {
        float av = bcast_lane(c1, j - 64);
        float s = fast_exp2(av);
        float w = (s - 1.0f) * __builtin_amdgcn_rcpf(s + 1.0f);
        if (lane == j - 64) wvL[b * 128 + j] = w;
        int off = lane + 63 - j;
        float tv = TpL[pj + ((off >= 0) ? off : 0)];
        c1 += ((off >= 0) ? tv : 0.0f) * w;
        pj += 127 - j;
      }
      float w0 = wvL[b * 128 + 2 * lane], w1 = wvL[b * 128 + 2 * lane + 1];
      wvhL[b * 64 + lane] = pack_f16(w0, w1);
    } else if (tid >= 448) {
      int l = tid - 448, b = l >> 5, k = l & 31;
      xuhL[b * 160 + 128 + k] = pack_f16(unx, uny);
    }
    __syncthreads();  // B2: wvh + next-u ready

    if (r >= 128 && r < 448) {
      const uint4* wp0 = (const uint4*)(wvhL);
      const uint4* wp1 = (const uint4*)(wvhL + 64);
      const int rr = r - 128;  // 0..319
      const uint* orow = OmL + rr * 65;
#pragma unroll
      for (int i = 0; i < 16; ++i) {
        const uint m0 = orow[i * 4 + 0], m1 = orow[i * 4 + 1];
        const uint m2 = orow[i * 4 + 2], m3 = orow[i * 4 + 3];
        const uint4 p = wp0[i], q = wp1[i];
        a0 = fdot2(m0, p.x, a0); a0 = fdot2(m1, p.y, a0);
        a0 = fdot2(m2, p.z, a0); a0 = fdot2(m3, p.w, a0);
        a1 = fdot2(m0, q.x, a1); a1 = fdot2(m1, q.y, a1);
        a1 = fdot2(m2, q.z, a1); a1 = fdot2(m3, q.w, a1);
      }
      if (r < 384) {
        float n0 = __shfl_down(a0, 1, 64);
        float n1 = __shfl_down(a1, 1, 64);
        if ((rr & 1) == 0) {
          xuhL[0 * 160 + (rr >> 1)] = pack_f16(a0, n0);
          xuhL[1 * 160 + (rr >> 1)] = pack_f16(a1, n1);
        }
      } else {
        const int o = r - 384;
        size_t base = ((size_t)bb * HORN + (t + 1)) * DOUTN + o;
        out[base] = a0;
        out[base + (size_t)HORN * DOUTN] = a1;
      }
    }
    __syncthreads();  // B3: xuh ready for next step
  }
}

// ---------------- host ----------------
extern "C" void kernel_launch(void* const* d_in, const int* in_sizes, int n_in,
                              void* d_out, int out_size, void* d_ws, size_t ws_size,
                              hipStream_t stream) {
  (void)in_sizes; (void)n_in; (void)out_size; (void)ws_size;
  const float* u_in = (const float*)d_in[0];
  const float* X    = (const float*)d_in[1];
  const float* Y    = (const float*)d_in[2];
  const float* B2   = (const float*)d_in[3];
  const float* C2   = (const float*)d_in[4];
  const float* D21  = (const float*)d_in[5];
  const float* D12  = (const float*)d_in[6];
  float* out = (float*)d_out;

  double* H    = (double*)d_ws;            // 640*640
  double* E    = H + 640 * 640;            // 256*256
  double* Ai   = E + 256 * 256;            // 128*128
  double* CMm  = Ai + 128 * 128;
  double* MBm  = CMm + 128 * 128;
  double* Sm   = MBm + 128 * 128;
  double* Tm   = Sm + 128 * 128;
  double* Einv = Tm + 128 * 128;           // 256*256
  double* Axwu = Einv + 256 * 256;         // 256*448
  double* G    = Axwu + 256 * 448;         // 64*448
  double* B2d  = G + 64 * 448;             // 256*64
  double* C2d  = B2d + 256 * 64;           // 64*256
  double* Dxt  = C2d + 64 * 256;           // 64*448
  double* Eye2 = Dxt + 64 * 448;           // 128*128
  double* M0d  = Eye2 + 128 * 128;
  double* Rb   = M0d + 128 * 128;
  double* scv  = Rb + 128 * 128;           // 128
  float*  F32  = (float*)(scv + 128);      // 128*128
  uint*   Msh  = (uint*)(F32 + 128 * 128); // 71680
  uint*   OmWh = Msh + 71680;              // 20480
  float*  TpP  = (float*)(OmWh + 20480);   // 8128

  dim3 blk16(16, 16);
  k_xtx<<<dim3(40, 40), blk16, 0, stream>>>(X, H);
  k_prep<<<561, 256, 0, stream>>>(H, Y, B2, C2, D21, E, scv, B2d, C2d, Dxt, Eye2);

  auto inv128 = [&](const double* A, int lda, double* Out) {
    k_ginv32<<<1, 256, 0, stream>>>(A, lda, F32);
    k_cast_f2d<<<64, 256, 0, stream>>>(F32, M0d, 128 * 128);
    // one Newton-Schulz refinement: M <- M0(2I - A M0)
    k_dgemm<<<dim3(8, 8), blk16, 0, stream>>>(128, 128, 128, A, lda, M0d, 128, -1.0, Eye2, 128, 1.0, Rb, 128);
    k_dgemm<<<dim3(8, 8), blk16, 0, stream>>>(128, 128, 128, M0d, 128, Rb, 128, 1.0, (const double*)nullptr, 0, 0.0, Out, 128);
  };

  const double* EA = E;
  const double* EB = E + 128;
  const double* EC = E + 128 * 256;
  const double* ED = E + 128 * 256 + 128;

  inv128(EA, 256, Ai);
  k_dgemm<<<dim3(8, 8), blk16, 0, stream>>>(128, 128, 128, EC, 256, Ai, 128, 1.0, (const double*)nullptr, 0, 0.0, CMm, 128);
  k_dgemm<<<dim3(8, 8), blk16, 0, stream>>>(128, 128, 128, Ai, 128, EB, 256, 1.0, (const double*)nullptr, 0, 0.0, MBm, 128);
  k_dgemm<<<dim3(8, 8), blk16, 0, stream>>>(128, 128, 128, CMm, 128, EB, 256, -1.0, ED, 256, 1.0, Sm, 128);
  inv128(Sm, 128, Tm);
  k_dgemm<<<dim3(8, 8), blk16, 0, stream>>>(128, 128, 128, Tm, 128, CMm, 128, -1.0, (const double*)nullptr, 0, 0.0, Einv + 128 * 256, 256);
  k_dgemm<<<dim3(8, 8), blk16, 0, stream>>>(128, 128, 128, MBm, 128, Tm, 128, -1.0, (const double*)nullptr, 0, 0.0, Einv + 128, 256);
  k_dgemm<<<dim3(8, 8), blk16, 0, stream>>>(128, 128, 128, MBm, 128, Einv + 128 * 256, 256, -1.0, Ai, 128, 1.0, Einv, 256);
  k_copyblk<<<64, 256, 0, stream>>>(Tm, 128, Einv + 128 * 256 + 128, 256, 128 * 128, 128);

  // Axwu = Einv @ [Fm | B1 | B2]
  k_dgemm<<<dim3(24, 16), blk16, 0, stream>>>(256, 384, 256, Einv, 256, H + 384 * NTWO, NTWO, 1.0, (const double*)nullptr, 0, 0.0, Axwu, 448);
  k_dgemm<<<dim3(4, 16), blk16, 0, stream>>>(256, 64, 256, Einv, 256, B2d, 64, 1.0, (const double*)nullptr, 0, 0.0, Axwu + 384, 448);
  // G = C2 @ Axwu + [0 | D21 | 0]
  k_dgemm<<<dim3(28, 4), blk16, 0, stream>>>(64, 448, 256, C2d, 256, Axwu, 448, 1.0, Dxt, 448, 1.0, G, 448);

  k_pack<<<424, 256, 0, stream>>>(H, D12, scv, Axwu, G, Msh, OmWh, TpP);

  k_scan<<<BATCHN / 2, 512, 0, stream>>>(u_in, Msh, OmWh, TpP, out);
}

// Round 4
// 8594.099 us; speedup vs baseline: 3.0365x; 1.0035x over previous
//
#include <hip/hip_runtime.h>
#include <math.h>
#include <stddef.h>

#define NTWO 640
#define DXN 256
#define DNLN 128
#define DINN 64
#define DOUTN 64
#define BATCHN 512
#define HORN 512
#define EPSV 1.0e-3

typedef unsigned int uint;
typedef unsigned short ushort;
typedef _Float16 half2_t __attribute__((ext_vector_type(2)));

__device__ __forceinline__ float fdot2(uint a, uint b, float c) {
#if __has_builtin(__builtin_amdgcn_fdot2)
  return __builtin_amdgcn_fdot2(__builtin_bit_cast(half2_t, a),
                                __builtin_bit_cast(half2_t, b), c, false);
#else
  half2_t x = __builtin_bit_cast(half2_t, a), y = __builtin_bit_cast(half2_t, b);
  return c + (float)x[0] * (float)y[0] + (float)x[1] * (float)y[1];
#endif
}

__device__ __forceinline__ uint pack_f16(float x, float y) {
  _Float16 hx = (_Float16)x, hy = (_Float16)y;
  ushort ux = __builtin_bit_cast(ushort, hx), uy = __builtin_bit_cast(ushort, hy);
  return ((uint)uy << 16) | (uint)ux;
}

__device__ __forceinline__ float fast_exp2(float x) {
#if __has_builtin(__builtin_amdgcn_exp2f)
  return __builtin_amdgcn_exp2f(x);
#else
  return exp2f(x);
#endif
}

__device__ __forceinline__ float bcast_lane(float v, int l) {
#if __has_builtin(__builtin_amdgcn_readlane)
  return __builtin_bit_cast(float, __builtin_amdgcn_readlane(__builtin_bit_cast(int, v), l));
#else
  return __shfl(v, l, 64);
#endif
}

// ---------------- precompute kernels (one-time, f64) ----------------

__global__ void k_xtx(const float* __restrict__ X, double* __restrict__ H) {
  __shared__ float sA[16][17];
  __shared__ float sB[16][17];
  const int tx = threadIdx.x, ty = threadIdx.y;
  const int bi = blockIdx.y * 16, bj = blockIdx.x * 16;
  double acc = 0.0;
  for (int k0 = 0; k0 < NTWO; k0 += 16) {
    sA[ty][tx] = X[(k0 + ty) * NTWO + bi + tx];
    sB[ty][tx] = X[(k0 + ty) * NTWO + bj + tx];
    __syncthreads();
#pragma unroll
    for (int kk = 0; kk < 16; ++kk)
      acc += (double)sA[kk][ty] * (double)sB[kk][tx];
    __syncthreads();
  }
  const int i = bi + ty, j = bj + tx;
  if (i == j) acc += EPSV;
  H[i * NTWO + j] = acc;
}

// fused small prep: E, sc, B2 cast, C2 cast, Dxt, Eye2
__global__ void k_prep(const double* __restrict__ H, const float* __restrict__ Y,
                       const float* __restrict__ B2, const float* __restrict__ C2,
                       const float* __restrict__ D21,
                       double* __restrict__ E, double* __restrict__ scv,
                       double* __restrict__ B2d, double* __restrict__ C2d,
                       double* __restrict__ Dxt, double* __restrict__ Eye2) {
  int idx = blockIdx.x * 256 + threadIdx.x;
  if (idx < 65536) {
    int i = idx >> 8, j = idx & 255;
    E[idx] = 0.5 * (H[i * NTWO + j] + H[(384 + i) * NTWO + 384 + j]
                    + (double)Y[i * 256 + j] - (double)Y[j * 256 + i]);
    return;
  }
  idx -= 65536;
  if (idx < 128) {
    double lam = 0.5 * H[(256 + idx) * NTWO + 256 + idx];
    scv[idx] = 2.8853900817779268 / lam;
    return;
  }
  idx -= 128;
  if (idx < 16384) { B2d[idx] = (double)B2[idx]; return; }
  idx -= 16384;
  if (idx < 16384) { C2d[idx] = (double)C2[idx]; return; }
  idx -= 16384;
  if (idx < 28672) {
    int r = idx / 448, c = idx % 448;
    double v = 0.0;
    if (c >= 256 && c < 384) v = (double)D21[r * 128 + (c - 256)];
    Dxt[idx] = v;
    return;
  }
  idx -= 28672;
  if (idx < 16384) {
    int r = idx >> 7, c = idx & 127;
    Eye2[idx] = (r == c) ? 2.0 : 0.0;
  }
}

// fp32 Gauss-Jordan inverse of 128x128 (no pivot; symmetric-part-PD input).
__global__ void k_ginv32(const double* __restrict__ A, int lda, float* __restrict__ Out) {
  __shared__ float M[128 * 129];
  const int tid = threadIdx.x;
  for (int i = tid; i < 128 * 128; i += 256)
    M[(i >> 7) * 129 + (i & 127)] = (float)A[(i >> 7) * lda + (i & 127)];
  __syncthreads();
  for (int k = 0; k < 128; ++k) {
    float ip = 1.0f / M[k * 129 + k];
    __syncthreads();
    if (tid < 128) {
      float v = M[k * 129 + tid];
      M[k * 129 + tid] = (tid == k) ? ip : v * ip;
    }
    __syncthreads();
    const int i0 = tid >> 1, half = tid & 1;
    float f = (i0 != k) ? M[i0 * 129 + k] : 0.0f;
    __syncthreads();
    if (i0 != k) {
      const float* rk = M + k * 129;
      float* ri = M + i0 * 129;
      const int j0 = half * 64;
#pragma unroll 8
      for (int j = j0; j < j0 + 64; ++j) {
        float v = (j == k) ? 0.0f : ri[j];
        ri[j] = v - f * rk[j];
      }
    }
    __syncthreads();
  }
  for (int i = tid; i < 128 * 128; i += 256) Out[i] = M[(i >> 7) * 129 + (i & 127)];
}

__global__ void k_dgemm(int M, int N, int K,
                        const double* __restrict__ A, int lda,
                        const double* __restrict__ B, int ldb,
                        double alpha,
                        const double* __restrict__ D, int ldd, double beta,
                        double* __restrict__ C, int ldc) {
  __shared__ double sA[16][17];
  __shared__ double sB[16][17];
  const int tx = threadIdx.x, ty = threadIdx.y;
  const int row = blockIdx.y * 16 + ty, col = blockIdx.x * 16 + tx;
  double acc = 0.0;
  for (int k0 = 0; k0 < K; k0 += 16) {
    sA[ty][tx] = A[row * lda + k0 + tx];
    sB[ty][tx] = B[(k0 + ty) * ldb + col];
    __syncthreads();
#pragma unroll
    for (int kk = 0; kk < 16; ++kk) acc += sA[ty][kk] * sB[kk][tx];
    __syncthreads();
  }
  double v = alpha * acc;
  if (beta != 0.0) v += beta * D[row * ldd + col];
  C[row * ldc + col] = v;
}

__global__ void k_copyblk(const double* __restrict__ S, int lds,
                          double* __restrict__ Dst, int ldd, int total, int cols) {
  int idx = blockIdx.x * 256 + threadIdx.x;
  if (idx < total) {
    int r = idx / cols, c = idx % cols;
    Dst[r * ldd + c] = S[r * lds + c];
  }
}

__global__ void k_cast_f2d(const float* __restrict__ s, double* __restrict__ d, int n) {
  int i = blockIdx.x * 256 + threadIdx.x;
  if (i < n) d[i] = (double)s[i];
}

// fused pack: Msh (448x320 f16, k-major dwords), OmWh (320x128 f16 k-major), TpP
__global__ void k_pack(const double* __restrict__ H, const float* __restrict__ D12,
                       const double* __restrict__ sc, const double* __restrict__ Axwu,
                       const double* __restrict__ G,
                       uint* __restrict__ Msh, uint* __restrict__ OmWh,
                       float* __restrict__ TpP) {
  int idx = blockIdx.x * 256 + threadIdx.x;
  if (idx < 448 * 160) {
    int rr = idx / 160, d = idx % 160;
    float v[2];
#pragma unroll
    for (int e = 0; e < 2; ++e) {
      int k = 2 * d + e;
      double x;
      if (rr < 128) {
        double s = sc[rr];
        x = (k < 256) ? (-H[(256 + rr) * NTWO + k] * s)
                      : ((double)D12[rr * DINN + (k - 256)] * s);
      } else {
        int r2 = rr - 128;
        const double* src = (r2 < 256) ? (Axwu + (size_t)r2 * 448) : (G + (size_t)(r2 - 256) * 448);
        x = (k < 256) ? src[k] : src[384 + (k - 256)];
      }
      v[e] = (float)x;
    }
    Msh[((size_t)(d >> 2) * 448 + rr) * 4 + (d & 3)] = pack_f16(v[0], v[1]);
    return;
  }
  idx -= 448 * 160;
  if (idx < 320 * 64) {
    int rr = idx / 64, d = idx % 64;
    float v[2];
#pragma unroll
    for (int e = 0; e < 2; ++e) {
      int j = 2 * d + e;
      double x = (rr < 256) ? Axwu[(size_t)rr * 448 + 256 + j]
                            : G[(size_t)(rr - 256) * 448 + 256 + j];
      v[e] = (float)x;
    }
    OmWh[((size_t)(d >> 2) * 320 + rr) * 4 + (d & 3)] = pack_f16(v[0], v[1]);
    return;
  }
  idx -= 320 * 64;
  if (idx < 16384) {
    int j = idx >> 7, c = idx & 127;
    if (c > j) {
      int pidx = 127 * j - (j * (j - 1)) / 2 + (c - j - 1);
      TpP[pidx] = (float)(-H[(256 + c) * NTWO + 256 + j] * sc[c]);
    }
  }
}

// ---------------- main scan: 256 WGs x 448 threads, NB=2 ----------------
// Msh row pinned in per-thread VGPRs (asm keep); OmW in LDS stride-65;
// u prefetch folded into threads 384-447.
__global__ __launch_bounds__(448, 2)
void k_scan(const float* __restrict__ u_in, const uint* __restrict__ Msh,
            const uint* __restrict__ OmWh, const float* __restrict__ TpP,
            float* __restrict__ out) {
  __shared__ float accL[2 * 128];
  __shared__ float wvL[2 * 128];
  __shared__ uint __align__(16) wvhL[2 * 64];
  __shared__ uint __align__(16) xuhL[2 * 160];
  __shared__ float TpL[8128];
  __shared__ uint OmL[320 * 65];  // row rr at OmL[rr*65 .. rr*65+63]
  const int tid = threadIdx.x;
  const int bb = blockIdx.x * 2;

  for (int i = tid; i < 8128; i += 448) TpL[i] = TpP[i];
  for (int idx = tid; idx < 320 * 16; idx += 448) {
    const int i = idx / 320, rr = idx % 320;
    const uint4 v = ((const uint4*)OmWh)[(size_t)i * 320 + rr];
    uint* p = OmL + rr * 65 + i * 4;
    p[0] = v.x; p[1] = v.y; p[2] = v.z; p[3] = v.w;
  }
  if (tid < 256) { int b = tid >> 7, k = tid & 127; xuhL[b * 160 + k] = 0u; }
  if (tid < 128) {
    int b = tid >> 6, o = tid & 63;
    out[((size_t)(bb + b) * HORN) * DOUTN + o] = 0.0f;
  }
  if (tid >= 384) {
    int l = tid - 384, b = l >> 5, k = l & 31;
    const float* up = u_in + ((size_t)(bb + b) * HORN) * DINN + 2 * k;
    xuhL[b * 160 + 128 + k] = pack_f16(up[0], up[1]);
  }

  // load this thread's Msh row into registers (40 x uint4 = 160 VGPRs), pinned
  uint4 mr[40];
  {
    const uint4* __restrict__ mp = (const uint4*)Msh;
#pragma unroll
    for (int i = 0; i < 40; ++i) mr[i] = mp[(size_t)i * 448 + tid];
#pragma unroll
    for (int i = 0; i < 40; ++i)
      asm volatile("" : "+v"(mr[i].x), "+v"(mr[i].y), "+v"(mr[i].z), "+v"(mr[i].w));
  }
  __syncthreads();

  const int r = tid;
  float unx = 0.f, uny = 0.f;

  for (int t = 0; t < HORN - 1; ++t) {
    // u prefetch (threads 384-447), overlapped with their Phase-A dots
    if (tid >= 384) {
      int l = tid - 384, b = l >> 5, k = l & 31;
      const float* up = u_in + ((size_t)(bb + b) * HORN + (t + 1)) * DINN + 2 * k;
      unx = up[0]; uny = up[1];
    }
    // Phase A: all 448 threads, pure register x LDS-broadcast
    float a0 = 0.f, a1 = 0.f;
    {
      const uint4* z0 = (const uint4*)(xuhL);
      const uint4* z1 = (const uint4*)(xuhL + 160);
#pragma unroll
      for (int i = 0; i < 40; ++i) {
        const uint4 m = mr[i];
        const uint4 p = z0[i], q = z1[i];
        a0 = fdot2(m.x, p.x, a0); a0 = fdot2(m.y, p.y, a0);
        a0 = fdot2(m.z, p.z, a0); a0 = fdot2(m.w, p.w, a0);
        a1 = fdot2(m.x, q.x, a1); a1 = fdot2(m.y, q.y, a1);
        a1 = fdot2(m.z, q.z, a1); a1 = fdot2(m.w, q.w, a1);
      }
      if (r < 128) { accL[r] = a0; accL[128 + r] = a1; }
    }
    __syncthreads();  // B1: acc ready

    if (tid < 128) {
      const int b = tid >> 6, lane = tid & 63;
      float c0 = accL[b * 128 + lane];
      float c1 = accL[b * 128 + 64 + lane];
      int pj = 0;
      for (int j = 0; j < 64; ++j) {
        float av = bcast_lane(c0, j);
        float s = fast_exp2(av);
        float w = (s - 1.0f) * __builtin_amdgcn_rcpf(s + 1.0f);
        if (lane == j) wvL[b * 128 + j] = w;
        float tv0 = TpL[pj + ((lane > j) ? (lane - j - 1) : 0)];
        c0 += ((lane > j) ? tv0 : 0.0f) * w;
        c1 += TpL[pj + (lane + 63 - j)] * w;
        pj += 127 - j;
      }
      for (int j = 64; j < 128; ++j) {
        float av = bcast_lane(c1, j - 64);
        float s = fast_exp2(av);
        float w = (s - 1.0f) * __builtin_amdgcn_rcpf(s + 1.0f);
        if (lane == j - 64) wvL[b * 128 + j] = w;
        int off = lane + 63 - j;
        float tv = TpL[pj + ((off >= 0) ? off : 0)];
        c1 += ((off >= 0) ? tv : 0.0f) * w;
        pj += 127 - j;
      }
      float w0 = wvL[b * 128 + 2 * lane], w1 = wvL[b * 128 + 2 * lane + 1];
      wvhL[b * 64 + lane] = pack_f16(w0, w1);
    } else if (tid >= 384) {
      int l = tid - 384, b = l >> 5, k = l & 31;
      xuhL[b * 160 + 128 + k] = pack_f16(unx, uny);
    }
    __syncthreads();  // B2: wvh + next-u ready

    if (r >= 128) {
      const uint4* wp0 = (const uint4*)(wvhL);
      const uint4* wp1 = (const uint4*)(wvhL + 64);
      const int rr = r - 128;  // 0..319
      const uint* orow = OmL + rr * 65;
#pragma unroll
      for (int i = 0; i < 16; ++i) {
        const uint m0 = orow[i * 4 + 0], m1 = orow[i * 4 + 1];
        const uint m2 = orow[i * 4 + 2], m3 = orow[i * 4 + 3];
        const uint4 p = wp0[i], q = wp1[i];
        a0 = fdot2(m0, p.x, a0); a0 = fdot2(m1, p.y, a0);
        a0 = fdot2(m2, p.z, a0); a0 = fdot2(m3, p.w, a0);
        a1 = fdot2(m0, q.x, a1); a1 = fdot2(m1, q.y, a1);
        a1 = fdot2(m2, q.z, a1); a1 = fdot2(m3, q.w, a1);
      }
      if (r < 384) {
        float n0 = __shfl_down(a0, 1, 64);
        float n1 = __shfl_down(a1, 1, 64);
        if ((rr & 1) == 0) {
          xuhL[0 * 160 + (rr >> 1)] = pack_f16(a0, n0);
          xuhL[1 * 160 + (rr >> 1)] = pack_f16(a1, n1);
        }
      } else {
        const int o = r - 384;
        size_t base = ((size_t)bb * HORN + (t + 1)) * DOUTN + o;
        out[base] = a0;
        out[base + (size_t)HORN * DOUTN] = a1;
      }
    }
    __syncthreads();  // B3: xuh ready for next step
  }
}

// ---------------- host ----------------
extern "C" void kernel_launch(void* const* d_in, const int* in_sizes, int n_in,
                              void* d_out, int out_size, void* d_ws, size_t ws_size,
                              hipStream_t stream) {
  (void)in_sizes; (void)n_in; (void)out_size; (void)ws_size;
  const float* u_in = (const float*)d_in[0];
  const float* X    = (const float*)d_in[1];
  const float* Y    = (const float*)d_in[2];
  const float* B2   = (const float*)d_in[3];
  const float* C2   = (const float*)d_in[4];
  const float* D21  = (const float*)d_in[5];
  const float* D12  = (const float*)d_in[6];
  float* out = (float*)d_out;

  double* H    = (double*)d_ws;            // 640*640
  double* E    = H + 640 * 640;            // 256*256
  double* Ai   = E + 256 * 256;            // 128*128
  double* CMm  = Ai + 128 * 128;
  double* MBm  = CMm + 128 * 128;
  double* Sm   = MBm + 128 * 128;
  double* Tm   = Sm + 128 * 128;
  double* Einv = Tm + 128 * 128;           // 256*256
  double* Axwu = Einv + 256 * 256;         // 256*448
  double* G    = Axwu + 256 * 448;         // 64*448
  double* B2d  = G + 64 * 448;             // 256*64
  double* C2d  = B2d + 256 * 64;           // 64*256
  double* Dxt  = C2d + 64 * 256;           // 64*448
  double* Eye2 = Dxt + 64 * 448;           // 128*128
  double* M0d  = Eye2 + 128 * 128;
  double* Rb   = M0d + 128 * 128;
  double* scv  = Rb + 128 * 128;           // 128
  float*  F32  = (float*)(scv + 128);      // 128*128
  uint*   Msh  = (uint*)(F32 + 128 * 128); // 71680
  uint*   OmWh = Msh + 71680;              // 20480
  float*  TpP  = (float*)(OmWh + 20480);   // 8128

  dim3 blk16(16, 16);
  k_xtx<<<dim3(40, 40), blk16, 0, stream>>>(X, H);
  k_prep<<<561, 256, 0, stream>>>(H, Y, B2, C2, D21, E, scv, B2d, C2d, Dxt, Eye2);

  auto inv128 = [&](const double* A, int lda, double* Out) {
    k_ginv32<<<1, 256, 0, stream>>>(A, lda, F32);
    k_cast_f2d<<<64, 256, 0, stream>>>(F32, M0d, 128 * 128);
    // one Newton-Schulz refinement: M <- M0(2I - A M0)
    k_dgemm<<<dim3(8, 8), blk16, 0, stream>>>(128, 128, 128, A, lda, M0d, 128, -1.0, Eye2, 128, 1.0, Rb, 128);
    k_dgemm<<<dim3(8, 8), blk16, 0, stream>>>(128, 128, 128, M0d, 128, Rb, 128, 1.0, (const double*)nullptr, 0, 0.0, Out, 128);
  };

  const double* EA = E;
  const double* EB = E + 128;
  const double* EC = E + 128 * 256;
  const double* ED = E + 128 * 256 + 128;

  inv128(EA, 256, Ai);
  k_dgemm<<<dim3(8, 8), blk16, 0, stream>>>(128, 128, 128, EC, 256, Ai, 128, 1.0, (const double*)nullptr, 0, 0.0, CMm, 128);
  k_dgemm<<<dim3(8, 8), blk16, 0, stream>>>(128, 128, 128, Ai, 128, EB, 256, 1.0, (const double*)nullptr, 0, 0.0, MBm, 128);
  k_dgemm<<<dim3(8, 8), blk16, 0, stream>>>(128, 128, 128, CMm, 128, EB, 256, -1.0, ED, 256, 1.0, Sm, 128);
  inv128(Sm, 128, Tm);
  k_dgemm<<<dim3(8, 8), blk16, 0, stream>>>(128, 128, 128, Tm, 128, CMm, 128, -1.0, (const double*)nullptr, 0, 0.0, Einv + 128 * 256, 256);
  k_dgemm<<<dim3(8, 8), blk16, 0, stream>>>(128, 128, 128, MBm, 128, Tm, 128, -1.0, (const double*)nullptr, 0, 0.0, Einv + 128, 256);
  k_dgemm<<<dim3(8, 8), blk16, 0, stream>>>(128, 128, 128, MBm, 128, Einv + 128 * 256, 256, -1.0, Ai, 128, 1.0, Einv, 256);
  k_copyblk<<<64, 256, 0, stream>>>(Tm, 128, Einv + 128 * 256 + 128, 256, 128 * 128, 128);

  // Axwu = Einv @ [Fm | B1 | B2]
  k_dgemm<<<dim3(24, 16), blk16, 0, stream>>>(256, 384, 256, Einv, 256, H + 384 * NTWO, NTWO, 1.0, (const double*)nullptr, 0, 0.0, Axwu, 448);
  k_dgemm<<<dim3(4, 16), blk16, 0, stream>>>(256, 64, 256, Einv, 256, B2d, 64, 1.0, (const double*)nullptr, 0, 0.0, Axwu + 384, 448);
  // G = C2 @ Axwu + [0 | D21 | 0]
  k_dgemm<<<dim3(28, 4), blk16, 0, stream>>>(64, 448, 256, C2d, 256, Axwu, 448, 1.0, Dxt, 448, 1.0, G, 448);

  k_pack<<<424, 256, 0, stream>>>(H, D12, scv, Axwu, G, Msh, OmWh, TpP);

  k_scan<<<BATCHN / 2, 448, 0, stream>>>(u_in, Msh, OmWh, TpP, out);
}

// Round 5
// 8272.132 us; speedup vs baseline: 3.1547x; 1.0389x over previous
//
#include <hip/hip_runtime.h>
#include <math.h>
#include <stddef.h>

#define NTWO 640
#define DXN 256
#define DNLN 128
#define DINN 64
#define DOUTN 64
#define BATCHN 512
#define HORN 512
#define EPSV 1.0e-3

typedef unsigned int uint;
typedef unsigned short ushort;
typedef _Float16 half2_t __attribute__((ext_vector_type(2)));

__device__ __forceinline__ float fdot2(uint a, uint b, float c) {
#if __has_builtin(__builtin_amdgcn_fdot2)
  return __builtin_amdgcn_fdot2(__builtin_bit_cast(half2_t, a),
                                __builtin_bit_cast(half2_t, b), c, false);
#else
  half2_t x = __builtin_bit_cast(half2_t, a), y = __builtin_bit_cast(half2_t, b);
  return c + (float)x[0] * (float)y[0] + (float)x[1] * (float)y[1];
#endif
}

__device__ __forceinline__ uint pack_f16(float x, float y) {
  _Float16 hx = (_Float16)x, hy = (_Float16)y;
  ushort ux = __builtin_bit_cast(ushort, hx), uy = __builtin_bit_cast(ushort, hy);
  return ((uint)uy << 16) | (uint)ux;
}

__device__ __forceinline__ float fast_exp2(float x) {
#if __has_builtin(__builtin_amdgcn_exp2f)
  return __builtin_amdgcn_exp2f(x);
#else
  return exp2f(x);
#endif
}

__device__ __forceinline__ float bcast_lane(float v, int l) {
#if __has_builtin(__builtin_amdgcn_readlane)
  return __builtin_bit_cast(float, __builtin_amdgcn_readlane(__builtin_bit_cast(int, v), l));
#else
  return __shfl(v, l, 64);
#endif
}

// ---------------- precompute kernels (one-time, f64) ----------------

__global__ void k_xtx(const float* __restrict__ X, double* __restrict__ H) {
  __shared__ float sA[16][17];
  __shared__ float sB[16][17];
  const int tx = threadIdx.x, ty = threadIdx.y;
  const int bi = blockIdx.y * 16, bj = blockIdx.x * 16;
  double acc = 0.0;
  for (int k0 = 0; k0 < NTWO; k0 += 16) {
    sA[ty][tx] = X[(k0 + ty) * NTWO + bi + tx];
    sB[ty][tx] = X[(k0 + ty) * NTWO + bj + tx];
    __syncthreads();
#pragma unroll
    for (int kk = 0; kk < 16; ++kk)
      acc += (double)sA[kk][ty] * (double)sB[kk][tx];
    __syncthreads();
  }
  const int i = bi + ty, j = bj + tx;
  if (i == j) acc += EPSV;
  H[i * NTWO + j] = acc;
}

// fused small prep: E, sc, B2 cast, C2 cast, Dxt, Eye2
__global__ void k_prep(const double* __restrict__ H, const float* __restrict__ Y,
                       const float* __restrict__ B2, const float* __restrict__ C2,
                       const float* __restrict__ D21,
                       double* __restrict__ E, double* __restrict__ scv,
                       double* __restrict__ B2d, double* __restrict__ C2d,
                       double* __restrict__ Dxt, double* __restrict__ Eye2) {
  int idx = blockIdx.x * 256 + threadIdx.x;
  if (idx < 65536) {
    int i = idx >> 8, j = idx & 255;
    E[idx] = 0.5 * (H[i * NTWO + j] + H[(384 + i) * NTWO + 384 + j]
                    + (double)Y[i * 256 + j] - (double)Y[j * 256 + i]);
    return;
  }
  idx -= 65536;
  if (idx < 128) {
    double lam = 0.5 * H[(256 + idx) * NTWO + 256 + idx];
    scv[idx] = 2.8853900817779268 / lam;
    return;
  }
  idx -= 128;
  if (idx < 16384) { B2d[idx] = (double)B2[idx]; return; }
  idx -= 16384;
  if (idx < 16384) { C2d[idx] = (double)C2[idx]; return; }
  idx -= 16384;
  if (idx < 28672) {
    int r = idx / 448, c = idx % 448;
    double v = 0.0;
    if (c >= 256 && c < 384) v = (double)D21[r * 128 + (c - 256)];
    Dxt[idx] = v;
    return;
  }
  idx -= 28672;
  if (idx < 16384) {
    int r = idx >> 7, c = idx & 127;
    Eye2[idx] = (r == c) ? 2.0 : 0.0;
  }
}

// fp32 Gauss-Jordan inverse of 128x128 (no pivot; symmetric-part-PD input).
__global__ void k_ginv32(const double* __restrict__ A, int lda, float* __restrict__ Out) {
  __shared__ float M[128 * 129];
  const int tid = threadIdx.x;
  for (int i = tid; i < 128 * 128; i += 256)
    M[(i >> 7) * 129 + (i & 127)] = (float)A[(i >> 7) * lda + (i & 127)];
  __syncthreads();
  for (int k = 0; k < 128; ++k) {
    float ip = 1.0f / M[k * 129 + k];
    __syncthreads();
    if (tid < 128) {
      float v = M[k * 129 + tid];
      M[k * 129 + tid] = (tid == k) ? ip : v * ip;
    }
    __syncthreads();
    const int i0 = tid >> 1, half = tid & 1;
    float f = (i0 != k) ? M[i0 * 129 + k] : 0.0f;
    __syncthreads();
    if (i0 != k) {
      const float* rk = M + k * 129;
      float* ri = M + i0 * 129;
      const int j0 = half * 64;
#pragma unroll 8
      for (int j = j0; j < j0 + 64; ++j) {
        float v = (j == k) ? 0.0f : ri[j];
        ri[j] = v - f * rk[j];
      }
    }
    __syncthreads();
  }
  for (int i = tid; i < 128 * 128; i += 256) Out[i] = M[(i >> 7) * 129 + (i & 127)];
}

__global__ void k_dgemm(int M, int N, int K,
                        const double* __restrict__ A, int lda,
                        const double* __restrict__ B, int ldb,
                        double alpha,
                        const double* __restrict__ D, int ldd, double beta,
                        double* __restrict__ C, int ldc) {
  __shared__ double sA[16][17];
  __shared__ double sB[16][17];
  const int tx = threadIdx.x, ty = threadIdx.y;
  const int row = blockIdx.y * 16 + ty, col = blockIdx.x * 16 + tx;
  double acc = 0.0;
  for (int k0 = 0; k0 < K; k0 += 16) {
    sA[ty][tx] = A[row * lda + k0 + tx];
    sB[ty][tx] = B[(k0 + ty) * ldb + col];
    __syncthreads();
#pragma unroll
    for (int kk = 0; kk < 16; ++kk) acc += sA[ty][kk] * sB[kk][tx];
    __syncthreads();
  }
  double v = alpha * acc;
  if (beta != 0.0) v += beta * D[row * ldd + col];
  C[row * ldc + col] = v;
}

__global__ void k_copyblk(const double* __restrict__ S, int lds,
                          double* __restrict__ Dst, int ldd, int total, int cols) {
  int idx = blockIdx.x * 256 + threadIdx.x;
  if (idx < total) {
    int r = idx / cols, c = idx % cols;
    Dst[r * ldd + c] = S[r * lds + c];
  }
}

__global__ void k_cast_f2d(const float* __restrict__ s, double* __restrict__ d, int n) {
  int i = blockIdx.x * 256 + threadIdx.x;
  if (i < n) d[i] = (double)s[i];
}

// fused pack: Msh (448x320 f16, k-major dwords), OmWh (320x128 f16 k-major), TpP
__global__ void k_pack(const double* __restrict__ H, const float* __restrict__ D12,
                       const double* __restrict__ sc, const double* __restrict__ Axwu,
                       const double* __restrict__ G,
                       uint* __restrict__ Msh, uint* __restrict__ OmWh,
                       float* __restrict__ TpP) {
  int idx = blockIdx.x * 256 + threadIdx.x;
  if (idx < 448 * 160) {
    int rr = idx / 160, d = idx % 160;
    float v[2];
#pragma unroll
    for (int e = 0; e < 2; ++e) {
      int k = 2 * d + e;
      double x;
      if (rr < 128) {
        double s = sc[rr];
        x = (k < 256) ? (-H[(256 + rr) * NTWO + k] * s)
                      : ((double)D12[rr * DINN + (k - 256)] * s);
      } else {
        int r2 = rr - 128;
        const double* src = (r2 < 256) ? (Axwu + (size_t)r2 * 448) : (G + (size_t)(r2 - 256) * 448);
        x = (k < 256) ? src[k] : src[384 + (k - 256)];
      }
      v[e] = (float)x;
    }
    Msh[((size_t)(d >> 2) * 448 + rr) * 4 + (d & 3)] = pack_f16(v[0], v[1]);
    return;
  }
  idx -= 448 * 160;
  if (idx < 320 * 64) {
    int rr = idx / 64, d = idx % 64;
    float v[2];
#pragma unroll
    for (int e = 0; e < 2; ++e) {
      int j = 2 * d + e;
      double x = (rr < 256) ? Axwu[(size_t)rr * 448 + 256 + j]
                            : G[(size_t)(rr - 256) * 448 + 256 + j];
      v[e] = (float)x;
    }
    OmWh[((size_t)(d >> 2) * 320 + rr) * 4 + (d & 3)] = pack_f16(v[0], v[1]);
    return;
  }
  idx -= 320 * 64;
  if (idx < 16384) {
    int j = idx >> 7, c = idx & 127;
    if (c > j) {
      int pidx = 127 * j - (j * (j - 1)) / 2 + (c - j - 1);
      TpP[pidx] = (float)(-H[(256 + c) * NTWO + 256 + j] * sc[c]);
    }
  }
}

// ---------------- main scan: 256 WGs x 448 threads, NB=2 ----------------
// Waves 0-1: per-sample base rows (lane, lane+64) streamed from L2, then the
// tanh chain runs IN-WAVE with no barrier; overlapped with waves 2-6 Phase A
// (rows 128..447 in pinned registers). 2 barriers/step.
__global__ __launch_bounds__(448)
__attribute__((amdgpu_waves_per_eu(2, 2)))
void k_scan(const float* __restrict__ u_in, const uint* __restrict__ Msh,
            const uint* __restrict__ OmWh, const float* __restrict__ TpP,
            float* __restrict__ out) {
  __shared__ uint __align__(16) wvhL[2 * 64];
  __shared__ uint __align__(16) xuhL[2 * 160];
  __shared__ float TpL[8128];
  __shared__ uint OmL[320 * 65];  // row rr at OmL[rr*65 .. rr*65+63]
  const int tid = threadIdx.x;
  const int bb = blockIdx.x * 2;

  for (int i = tid; i < 8128; i += 448) TpL[i] = TpP[i];
  for (int idx = tid; idx < 320 * 16; idx += 448) {
    const int i = idx / 320, rr = idx % 320;
    const uint4 v = ((const uint4*)OmWh)[(size_t)i * 320 + rr];
    uint* p = OmL + rr * 65 + i * 4;
    p[0] = v.x; p[1] = v.y; p[2] = v.z; p[3] = v.w;
  }
  if (tid < 256) { int b = tid >> 7, k = tid & 127; xuhL[b * 160 + k] = 0u; }
  if (tid < 128) {
    int b = tid >> 6, o = tid & 63;
    out[((size_t)(bb + b) * HORN) * DOUTN + o] = 0.0f;
  }
  if (tid >= 384) {
    int l = tid - 384, b = l >> 5, k = l & 31;
    const float* up = u_in + ((size_t)(bb + b) * HORN) * DINN + 2 * k;
    xuhL[b * 160 + 128 + k] = pack_f16(up[0], up[1]);
  }

  // waves 2-6: pin this thread's Msh row (rows 128..447) in registers
  uint4 mr[40];
  if (tid >= 128) {
    const uint4* __restrict__ mp = (const uint4*)Msh;
#pragma unroll
    for (int i = 0; i < 40; ++i) mr[i] = mp[(size_t)i * 448 + tid];
#pragma unroll
    for (int i = 0; i < 40; ++i)
      asm volatile("" : "+v"(mr[i].x), "+v"(mr[i].y), "+v"(mr[i].z), "+v"(mr[i].w));
  }
  __syncthreads();

  const int r = tid;
  float unx = 0.f, uny = 0.f;

  for (int t = 0; t < HORN - 1; ++t) {
    float a0 = 0.f, a1 = 0.f;
    if (tid < 128) {
      // ---- waves 0-1: base rows (l, l+64) for sample b, then chain in-wave
      const int b = tid >> 6, l = tid & 63;
      float c0 = 0.f, c1 = 0.f;
      {
        const uint4* __restrict__ mp = (const uint4*)Msh;
        const uint4* zz = (const uint4*)(xuhL + b * 160);
#pragma unroll 10
        for (int i = 0; i < 40; ++i) {
          const uint4 mA = mp[(size_t)i * 448 + l];
          const uint4 mB = mp[(size_t)i * 448 + 64 + l];
          const uint4 p = zz[i];
          c0 = fdot2(mA.x, p.x, c0); c0 = fdot2(mA.y, p.y, c0);
          c0 = fdot2(mA.z, p.z, c0); c0 = fdot2(mA.w, p.w, c0);
          c1 = fdot2(mB.x, p.x, c1); c1 = fdot2(mB.y, p.y, c1);
          c1 = fdot2(mB.z, p.z, c1); c1 = fdot2(mB.w, p.w, c1);
        }
      }
      // ---- chain (no barrier needed: c0/c1 produced in this wave)
      float wx = 0.f, wy = 0.f;
      int pj = 0;
#pragma unroll 4
      for (int j = 0; j < 64; ++j) {
        const float av = bcast_lane(c0, j);
        const float s = fast_exp2(av);
        const float rc = __builtin_amdgcn_rcpf(s + 1.0f);
        const float w = __builtin_fmaf(-2.0f, rc, 1.0f);
        if (l == (j >> 1)) { if (j & 1) wy = w; else wx = w; }
        const float tv0 = TpL[pj + ((l > j) ? (l - j - 1) : 0)];
        c0 += ((l > j) ? tv0 : 0.0f) * w;
        c1 += TpL[pj + (l + 63 - j)] * w;
        pj += 127 - j;
      }
#pragma unroll 4
      for (int j = 64; j < 128; ++j) {
        const float av = bcast_lane(c1, j - 64);
        const float s = fast_exp2(av);
        const float rc = __builtin_amdgcn_rcpf(s + 1.0f);
        const float w = __builtin_fmaf(-2.0f, rc, 1.0f);
        if (l == (j >> 1)) { if (j & 1) wy = w; else wx = w; }
        const int off = l + 63 - j;
        const float tv = TpL[pj + ((off >= 0) ? off : 0)];
        c1 += ((off >= 0) ? tv : 0.0f) * w;
        pj += 127 - j;
      }
      wvhL[b * 64 + l] = pack_f16(wx, wy);
    } else {
      // ---- waves 2-6: u prefetch + register Phase A (rows 128..447, both samples)
      if (tid >= 384) {
        int l = tid - 384, b = l >> 5, k = l & 31;
        const float* up = u_in + ((size_t)(bb + b) * HORN + (t + 1)) * DINN + 2 * k;
        unx = up[0]; uny = up[1];
      }
      const uint4* z0 = (const uint4*)(xuhL);
      const uint4* z1 = (const uint4*)(xuhL + 160);
#pragma unroll
      for (int i = 0; i < 40; ++i) {
        const uint4 m = mr[i];
        const uint4 p = z0[i], q = z1[i];
        a0 = fdot2(m.x, p.x, a0); a0 = fdot2(m.y, p.y, a0);
        a0 = fdot2(m.z, p.z, a0); a0 = fdot2(m.w, p.w, a0);
        a1 = fdot2(m.x, q.x, a1); a1 = fdot2(m.y, q.y, a1);
        a1 = fdot2(m.z, q.z, a1); a1 = fdot2(m.w, q.w, a1);
      }
    }
    __syncthreads();  // B2: wvh ready (chain waves); A done (all)

    if (r >= 128) {
      const uint4* wp0 = (const uint4*)(wvhL);
      const uint4* wp1 = (const uint4*)(wvhL + 64);
      const int rr = r - 128;  // 0..319
      const uint* orow = OmL + rr * 65;
#pragma unroll
      for (int i = 0; i < 16; ++i) {
        const uint m0 = orow[i * 4 + 0], m1 = orow[i * 4 + 1];
        const uint m2 = orow[i * 4 + 2], m3 = orow[i * 4 + 3];
        const uint4 p = wp0[i], q = wp1[i];
        a0 = fdot2(m0, p.x, a0); a0 = fdot2(m1, p.y, a0);
        a0 = fdot2(m2, p.z, a0); a0 = fdot2(m3, p.w, a0);
        a1 = fdot2(m0, q.x, a1); a1 = fdot2(m1, q.y, a1);
        a1 = fdot2(m2, q.z, a1); a1 = fdot2(m3, q.w, a1);
      }
      if (r < 384) {
        float n0 = __shfl_down(a0, 1, 64);
        float n1 = __shfl_down(a1, 1, 64);
        if ((rr & 1) == 0) {
          xuhL[0 * 160 + (rr >> 1)] = pack_f16(a0, n0);
          xuhL[1 * 160 + (rr >> 1)] = pack_f16(a1, n1);
        }
      } else {
        const int o = r - 384;
        size_t base = ((size_t)bb * HORN + (t + 1)) * DOUTN + o;
        out[base] = a0;
        out[base + (size_t)HORN * DOUTN] = a1;
        // commit next-step u
        int l = tid - 384, b = l >> 5, k = l & 31;
        xuhL[b * 160 + 128 + k] = pack_f16(unx, uny);
      }
    }
    __syncthreads();  // B3: xuh ready for next step
  }
}

// ---------------- host ----------------
extern "C" void kernel_launch(void* const* d_in, const int* in_sizes, int n_in,
                              void* d_out, int out_size, void* d_ws, size_t ws_size,
                              hipStream_t stream) {
  (void)in_sizes; (void)n_in; (void)out_size; (void)ws_size;
  const float* u_in = (const float*)d_in[0];
  const float* X    = (const float*)d_in[1];
  const float* Y    = (const float*)d_in[2];
  const float* B2   = (const float*)d_in[3];
  const float* C2   = (const float*)d_in[4];
  const float* D21  = (const float*)d_in[5];
  const float* D12  = (const float*)d_in[6];
  float* out = (float*)d_out;

  double* H    = (double*)d_ws;            // 640*640
  double* E    = H + 640 * 640;            // 256*256
  double* Ai   = E + 256 * 256;            // 128*128
  double* CMm  = Ai + 128 * 128;
  double* MBm  = CMm + 128 * 128;
  double* Sm   = MBm + 128 * 128;
  double* Tm   = Sm + 128 * 128;
  double* Einv = Tm + 128 * 128;           // 256*256
  double* Axwu = Einv + 256 * 256;         // 256*448
  double* G    = Axwu + 256 * 448;         // 64*448
  double* B2d  = G + 64 * 448;             // 256*64
  double* C2d  = B2d + 256 * 64;           // 64*256
  double* Dxt  = C2d + 64 * 256;           // 64*448
  double* Eye2 = Dxt + 64 * 448;           // 128*128
  double* M0d  = Eye2 + 128 * 128;
  double* Rb   = M0d + 128 * 128;
  double* scv  = Rb + 128 * 128;           // 128
  float*  F32  = (float*)(scv + 128);      // 128*128
  uint*   Msh  = (uint*)(F32 + 128 * 128); // 71680
  uint*   OmWh = Msh + 71680;              // 20480
  float*  TpP  = (float*)(OmWh + 20480);   // 8128

  dim3 blk16(16, 16);
  k_xtx<<<dim3(40, 40), blk16, 0, stream>>>(X, H);
  k_prep<<<561, 256, 0, stream>>>(H, Y, B2, C2, D21, E, scv, B2d, C2d, Dxt, Eye2);

  auto inv128 = [&](const double* A, int lda, double* Out) {
    k_ginv32<<<1, 256, 0, stream>>>(A, lda, F32);
    k_cast_f2d<<<64, 256, 0, stream>>>(F32, M0d, 128 * 128);
    // one Newton-Schulz refinement: M <- M0(2I - A M0)
    k_dgemm<<<dim3(8, 8), blk16, 0, stream>>>(128, 128, 128, A, lda, M0d, 128, -1.0, Eye2, 128, 1.0, Rb, 128);
    k_dgemm<<<dim3(8, 8), blk16, 0, stream>>>(128, 128, 128, M0d, 128, Rb, 128, 1.0, (const double*)nullptr, 0, 0.0, Out, 128);
  };

  const double* EA = E;
  const double* EB = E + 128;
  const double* EC = E + 128 * 256;
  const double* ED = E + 128 * 256 + 128;

  inv128(EA, 256, Ai);
  k_dgemm<<<dim3(8, 8), blk16, 0, stream>>>(128, 128, 128, EC, 256, Ai, 128, 1.0, (const double*)nullptr, 0, 0.0, CMm, 128);
  k_dgemm<<<dim3(8, 8), blk16, 0, stream>>>(128, 128, 128, Ai, 128, EB, 256, 1.0, (const double*)nullptr, 0, 0.0, MBm, 128);
  k_dgemm<<<dim3(8, 8), blk16, 0, stream>>>(128, 128, 128, CMm, 128, EB, 256, -1.0, ED, 256, 1.0, Sm, 128);
  inv128(Sm, 128, Tm);
  k_dgemm<<<dim3(8, 8), blk16, 0, stream>>>(128, 128, 128, Tm, 128, CMm, 128, -1.0, (const double*)nullptr, 0, 0.0, Einv + 128 * 256, 256);
  k_dgemm<<<dim3(8, 8), blk16, 0, stream>>>(128, 128, 128, MBm, 128, Tm, 128, -1.0, (const double*)nullptr, 0, 0.0, Einv + 128, 256);
  k_dgemm<<<dim3(8, 8), blk16, 0, stream>>>(128, 128, 128, MBm, 128, Einv + 128 * 256, 256, -1.0, Ai, 128, 1.0, Einv, 256);
  k_copyblk<<<64, 256, 0, stream>>>(Tm, 128, Einv + 128 * 256 + 128, 256, 128 * 128, 128);

  // Axwu = Einv @ [Fm | B1 | B2]
  k_dgemm<<<dim3(24, 16), blk16, 0, stream>>>(256, 384, 256, Einv, 256, H + 384 * NTWO, NTWO, 1.0, (const double*)nullptr, 0, 0.0, Axwu, 448);
  k_dgemm<<<dim3(4, 16), blk16, 0, stream>>>(256, 64, 256, Einv, 256, B2d, 64, 1.0, (const double*)nullptr, 0, 0.0, Axwu + 384, 448);
  // G = C2 @ Axwu + [0 | D21 | 0]
  k_dgemm<<<dim3(28, 4), blk16, 0, stream>>>(64, 448, 256, C2d, 256, Axwu, 448, 1.0, Dxt, 448, 1.0, G, 448);

  k_pack<<<424, 256, 0, stream>>>(H, D12, scv, Axwu, G, Msh, OmWh, TpP);

  k_scan<<<BATCHN / 2, 448, 0, stream>>>(u_in, Msh, OmWh, TpP, out);
}

// Round 6
// 7762.079 us; speedup vs baseline: 3.3620x; 1.0657x over previous
//
#include <hip/hip_runtime.h>
#include <math.h>
#include <stddef.h>

#define NTWO 640
#define DXN 256
#define DNLN 128
#define DINN 64
#define DOUTN 64
#define BATCHN 512
#define HORN 512
#define EPSV 1.0e-3

typedef unsigned int uint;
typedef unsigned short ushort;
typedef _Float16 half2_t __attribute__((ext_vector_type(2)));

__device__ __forceinline__ float fdot2(uint a, uint b, float c) {
#if __has_builtin(__builtin_amdgcn_fdot2)
  return __builtin_amdgcn_fdot2(__builtin_bit_cast(half2_t, a),
                                __builtin_bit_cast(half2_t, b), c, false);
#else
  half2_t x = __builtin_bit_cast(half2_t, a), y = __builtin_bit_cast(half2_t, b);
  return c + (float)x[0] * (float)y[0] + (float)x[1] * (float)y[1];
#endif
}

__device__ __forceinline__ uint pack_f16(float x, float y) {
  _Float16 hx = (_Float16)x, hy = (_Float16)y;
  ushort ux = __builtin_bit_cast(ushort, hx), uy = __builtin_bit_cast(ushort, hy);
  return ((uint)uy << 16) | (uint)ux;
}

__device__ __forceinline__ float fast_exp2(float x) {
#if __has_builtin(__builtin_amdgcn_exp2f)
  return __builtin_amdgcn_exp2f(x);
#else
  return exp2f(x);
#endif
}

__device__ __forceinline__ float bcast_lane(float v, int l) {
#if __has_builtin(__builtin_amdgcn_readlane)
  return __builtin_bit_cast(float, __builtin_amdgcn_readlane(__builtin_bit_cast(int, v), l));
#else
  return __shfl(v, l, 64);
#endif
}

// ---------------- precompute kernels (one-time, f64) ----------------

__global__ void k_xtx(const float* __restrict__ X, double* __restrict__ H) {
  __shared__ float sA[16][17];
  __shared__ float sB[16][17];
  const int tx = threadIdx.x, ty = threadIdx.y;
  const int bi = blockIdx.y * 16, bj = blockIdx.x * 16;
  double acc = 0.0;
  for (int k0 = 0; k0 < NTWO; k0 += 16) {
    sA[ty][tx] = X[(k0 + ty) * NTWO + bi + tx];
    sB[ty][tx] = X[(k0 + ty) * NTWO + bj + tx];
    __syncthreads();
#pragma unroll
    for (int kk = 0; kk < 16; ++kk)
      acc += (double)sA[kk][ty] * (double)sB[kk][tx];
    __syncthreads();
  }
  const int i = bi + ty, j = bj + tx;
  if (i == j) acc += EPSV;
  H[i * NTWO + j] = acc;
}

// fused small prep: E, sc, B2 cast, C2 cast, Dxt, Eye2
__global__ void k_prep(const double* __restrict__ H, const float* __restrict__ Y,
                       const float* __restrict__ B2, const float* __restrict__ C2,
                       const float* __restrict__ D21,
                       double* __restrict__ E, double* __restrict__ scv,
                       double* __restrict__ B2d, double* __restrict__ C2d,
                       double* __restrict__ Dxt, double* __restrict__ Eye2) {
  int idx = blockIdx.x * 256 + threadIdx.x;
  if (idx < 65536) {
    int i = idx >> 8, j = idx & 255;
    E[idx] = 0.5 * (H[i * NTWO + j] + H[(384 + i) * NTWO + 384 + j]
                    + (double)Y[i * 256 + j] - (double)Y[j * 256 + i]);
    return;
  }
  idx -= 65536;
  if (idx < 128) {
    double lam = 0.5 * H[(256 + idx) * NTWO + 256 + idx];
    scv[idx] = 2.8853900817779268 / lam;
    return;
  }
  idx -= 128;
  if (idx < 16384) { B2d[idx] = (double)B2[idx]; return; }
  idx -= 16384;
  if (idx < 16384) { C2d[idx] = (double)C2[idx]; return; }
  idx -= 16384;
  if (idx < 28672) {
    int r = idx / 448, c = idx % 448;
    double v = 0.0;
    if (c >= 256 && c < 384) v = (double)D21[r * 128 + (c - 256)];
    Dxt[idx] = v;
    return;
  }
  idx -= 28672;
  if (idx < 16384) {
    int r = idx >> 7, c = idx & 127;
    Eye2[idx] = (r == c) ? 2.0 : 0.0;
  }
}

// fp32 Gauss-Jordan inverse of 128x128 (no pivot; symmetric-part-PD input).
__global__ void k_ginv32(const double* __restrict__ A, int lda, float* __restrict__ Out) {
  __shared__ float M[128 * 129];
  const int tid = threadIdx.x;
  for (int i = tid; i < 128 * 128; i += 256)
    M[(i >> 7) * 129 + (i & 127)] = (float)A[(i >> 7) * lda + (i & 127)];
  __syncthreads();
  for (int k = 0; k < 128; ++k) {
    float ip = 1.0f / M[k * 129 + k];
    __syncthreads();
    if (tid < 128) {
      float v = M[k * 129 + tid];
      M[k * 129 + tid] = (tid == k) ? ip : v * ip;
    }
    __syncthreads();
    const int i0 = tid >> 1, half = tid & 1;
    float f = (i0 != k) ? M[i0 * 129 + k] : 0.0f;
    __syncthreads();
    if (i0 != k) {
      const float* rk = M + k * 129;
      float* ri = M + i0 * 129;
      const int j0 = half * 64;
#pragma unroll 8
      for (int j = j0; j < j0 + 64; ++j) {
        float v = (j == k) ? 0.0f : ri[j];
        ri[j] = v - f * rk[j];
      }
    }
    __syncthreads();
  }
  for (int i = tid; i < 128 * 128; i += 256) Out[i] = M[(i >> 7) * 129 + (i & 127)];
}

__global__ void k_dgemm(int M, int N, int K,
                        const double* __restrict__ A, int lda,
                        const double* __restrict__ B, int ldb,
                        double alpha,
                        const double* __restrict__ D, int ldd, double beta,
                        double* __restrict__ C, int ldc) {
  __shared__ double sA[16][17];
  __shared__ double sB[16][17];
  const int tx = threadIdx.x, ty = threadIdx.y;
  const int row = blockIdx.y * 16 + ty, col = blockIdx.x * 16 + tx;
  double acc = 0.0;
  for (int k0 = 0; k0 < K; k0 += 16) {
    sA[ty][tx] = A[row * lda + k0 + tx];
    sB[ty][tx] = B[(k0 + ty) * ldb + col];
    __syncthreads();
#pragma unroll
    for (int kk = 0; kk < 16; ++kk) acc += sA[ty][kk] * sB[kk][tx];
    __syncthreads();
  }
  double v = alpha * acc;
  if (beta != 0.0) v += beta * D[row * ldd + col];
  C[row * ldc + col] = v;
}

__global__ void k_copyblk(const double* __restrict__ S, int lds,
                          double* __restrict__ Dst, int ldd, int total, int cols) {
  int idx = blockIdx.x * 256 + threadIdx.x;
  if (idx < total) {
    int r = idx / cols, c = idx % cols;
    Dst[r * ldd + c] = S[r * lds + c];
  }
}

__global__ void k_cast_f2d(const float* __restrict__ s, double* __restrict__ d, int n) {
  int i = blockIdx.x * 256 + threadIdx.x;
  if (i < n) d[i] = (double)s[i];
}

// fused pack: Msh (448x320 f16, k-major dwords), OmWh (320x128 f16 k-major), TpP
__global__ void k_pack(const double* __restrict__ H, const float* __restrict__ D12,
                       const double* __restrict__ sc, const double* __restrict__ Axwu,
                       const double* __restrict__ G,
                       uint* __restrict__ Msh, uint* __restrict__ OmWh,
                       float* __restrict__ TpP) {
  int idx = blockIdx.x * 256 + threadIdx.x;
  if (idx < 448 * 160) {
    int rr = idx / 160, d = idx % 160;
    float v[2];
#pragma unroll
    for (int e = 0; e < 2; ++e) {
      int k = 2 * d + e;
      double x;
      if (rr < 128) {
        double s = sc[rr];
        x = (k < 256) ? (-H[(256 + rr) * NTWO + k] * s)
                      : ((double)D12[rr * DINN + (k - 256)] * s);
      } else {
        int r2 = rr - 128;
        const double* src = (r2 < 256) ? (Axwu + (size_t)r2 * 448) : (G + (size_t)(r2 - 256) * 448);
        x = (k < 256) ? src[k] : src[384 + (k - 256)];
      }
      v[e] = (float)x;
    }
    Msh[((size_t)(d >> 2) * 448 + rr) * 4 + (d & 3)] = pack_f16(v[0], v[1]);
    return;
  }
  idx -= 448 * 160;
  if (idx < 320 * 64) {
    int rr = idx / 64, d = idx % 64;
    float v[2];
#pragma unroll
    for (int e = 0; e < 2; ++e) {
      int j = 2 * d + e;
      double x = (rr < 256) ? Axwu[(size_t)rr * 448 + 256 + j]
                            : G[(size_t)(rr - 256) * 448 + 256 + j];
      v[e] = (float)x;
    }
    OmWh[((size_t)(d >> 2) * 320 + rr) * 4 + (d & 3)] = pack_f16(v[0], v[1]);
    return;
  }
  idx -= 320 * 64;
  if (idx < 16384) {
    int j = idx >> 7, c = idx & 127;
    if (c > j) {
      int pidx = 127 * j - (j * (j - 1)) / 2 + (c - j - 1);
      TpP[pidx] = (float)(-H[(256 + c) * NTWO + 256 + j] * sc[c]);
    }
  }
}

// ---------------- main scan: 512 WGs x 448 threads, NB=1, 2 blocks/CU ----------------
// Wave 0: base rows (l, l+64) streamed from L2, chain in-wave (no barrier).
// Waves 1-5: rows 128..447 streamed from L2 (one row/thread); threads 384-415
// prefetch u. Phase C streams OmW coalesced from L2. LDS ~34 KB -> 2 blocks/CU
// so one block's chain/latency overlaps the other block's matvec streams.
__global__ __launch_bounds__(448, 4)
void k_scan(const float* __restrict__ u_in, const uint* __restrict__ Msh,
            const uint* __restrict__ OmWh, const float* __restrict__ TpP,
            float* __restrict__ out) {
  __shared__ uint __align__(16) wvhL[64];
  __shared__ uint __align__(16) xuhL[160];
  __shared__ float TpL[8128];
  const int tid = threadIdx.x;
  const int s = blockIdx.x;  // sample

  for (int i = tid; i < 8128; i += 448) TpL[i] = TpP[i];
  if (tid < 128) xuhL[tid] = 0u;
  if (tid < 64) out[((size_t)s * HORN) * DOUTN + tid] = 0.0f;
  if (tid >= 384 && tid < 416) {
    int k = tid - 384;
    const float* up = u_in + ((size_t)s * HORN) * DINN + 2 * k;
    xuhL[128 + k] = pack_f16(up[0], up[1]);
  }
  __syncthreads();

  float unx = 0.f, uny = 0.f;

  for (int t = 0; t < HORN - 1; ++t) {
    float a0 = 0.f;
    if (tid < 64) {
      // ---- wave 0: base rows (l, l+64), then chain in-wave
      const int l = tid;
      float c0 = 0.f, c1 = 0.f;
      {
        const uint4* __restrict__ mp = (const uint4*)Msh;
        const uint4* zz = (const uint4*)xuhL;
#pragma unroll 10
        for (int i = 0; i < 40; ++i) {
          const uint4 mA = mp[(size_t)i * 448 + l];
          const uint4 mB = mp[(size_t)i * 448 + 64 + l];
          const uint4 p = zz[i];
          c0 = fdot2(mA.x, p.x, c0); c0 = fdot2(mA.y, p.y, c0);
          c0 = fdot2(mA.z, p.z, c0); c0 = fdot2(mA.w, p.w, c0);
          c1 = fdot2(mB.x, p.x, c1); c1 = fdot2(mB.y, p.y, c1);
          c1 = fdot2(mB.z, p.z, c1); c1 = fdot2(mB.w, p.w, c1);
        }
      }
      float wx = 0.f, wy = 0.f;
      int pj = 0;
#pragma unroll 4
      for (int j = 0; j < 64; ++j) {
        const float av = bcast_lane(c0, j);
        const float sx = fast_exp2(av);
        const float rc = __builtin_amdgcn_rcpf(sx + 1.0f);
        const float w = __builtin_fmaf(-2.0f, rc, 1.0f);
        if (l == (j >> 1)) { if (j & 1) wy = w; else wx = w; }
        const float tv0 = TpL[pj + ((l > j) ? (l - j - 1) : 0)];
        c0 += ((l > j) ? tv0 : 0.0f) * w;
        c1 += TpL[pj + (l + 63 - j)] * w;
        pj += 127 - j;
      }
#pragma unroll 4
      for (int j = 64; j < 128; ++j) {
        const float av = bcast_lane(c1, j - 64);
        const float sx = fast_exp2(av);
        const float rc = __builtin_amdgcn_rcpf(sx + 1.0f);
        const float w = __builtin_fmaf(-2.0f, rc, 1.0f);
        if (l == (j >> 1)) { if (j & 1) wy = w; else wx = w; }
        const int off = l + 63 - j;
        const float tv = TpL[pj + ((off >= 0) ? off : 0)];
        c1 += ((off >= 0) ? tv : 0.0f) * w;
        pj += 127 - j;
      }
      wvhL[l] = pack_f16(wx, wy);
    } else if (tid < 384) {
      // ---- waves 1-5: rows 128..447, one row per thread
      const int row = tid + 64;
      const uint4* __restrict__ mp = (const uint4*)Msh;
      const uint4* zz = (const uint4*)xuhL;
#pragma unroll 10
      for (int i = 0; i < 40; ++i) {
        const uint4 m = mp[(size_t)i * 448 + row];
        const uint4 p = zz[i];
        a0 = fdot2(m.x, p.x, a0); a0 = fdot2(m.y, p.y, a0);
        a0 = fdot2(m.z, p.z, a0); a0 = fdot2(m.w, p.w, a0);
      }
    } else {
      const int k = tid - 384;
      if (k < 32) {
        const float* up = u_in + ((size_t)s * HORN + (t + 1)) * DINN + 2 * k;
        unx = up[0]; uny = up[1];
      }
    }
    __syncthreads();  // B2: wvh + Phase A done

    if (tid >= 64 && tid < 384) {
      const int rr = tid - 64;  // OmW row 0..319
      const uint4* __restrict__ op = (const uint4*)OmWh;
      const uint4* wp = (const uint4*)wvhL;
#pragma unroll
      for (int i = 0; i < 16; ++i) {
        const uint4 m = op[(size_t)i * 320 + rr];
        const uint4 p = wp[i];
        a0 = fdot2(m.x, p.x, a0); a0 = fdot2(m.y, p.y, a0);
        a0 = fdot2(m.z, p.z, a0); a0 = fdot2(m.w, p.w, a0);
      }
      if (tid < 320) {
        // x rows 0..255 (rr == x index); pack pairs into f16 dwords
        const float n0 = __shfl_down(a0, 1, 64);
        if ((rr & 1) == 0) xuhL[rr >> 1] = pack_f16(a0, n0);
      } else {
        const int o = tid - 320;  // y rows
        out[((size_t)s * HORN + (t + 1)) * DOUTN + o] = a0;
      }
    } else if (tid >= 384 && tid < 416) {
      const int k = tid - 384;
      xuhL[128 + k] = pack_f16(unx, uny);
    }
    __syncthreads();  // B3: xuh ready for next step
  }
}

// ---------------- host ----------------
extern "C" void kernel_launch(void* const* d_in, const int* in_sizes, int n_in,
                              void* d_out, int out_size, void* d_ws, size_t ws_size,
                              hipStream_t stream) {
  (void)in_sizes; (void)n_in; (void)out_size; (void)ws_size;
  const float* u_in = (const float*)d_in[0];
  const float* X    = (const float*)d_in[1];
  const float* Y    = (const float*)d_in[2];
  const float* B2   = (const float*)d_in[3];
  const float* C2   = (const float*)d_in[4];
  const float* D21  = (const float*)d_in[5];
  const float* D12  = (const float*)d_in[6];
  float* out = (float*)d_out;

  double* H    = (double*)d_ws;            // 640*640
  double* E    = H + 640 * 640;            // 256*256
  double* Ai   = E + 256 * 256;            // 128*128
  double* CMm  = Ai + 128 * 128;
  double* MBm  = CMm + 128 * 128;
  double* Sm   = MBm + 128 * 128;
  double* Tm   = Sm + 128 * 128;
  double* Einv = Tm + 128 * 128;           // 256*256
  double* Axwu = Einv + 256 * 256;         // 256*448
  double* G    = Axwu + 256 * 448;         // 64*448
  double* B2d  = G + 64 * 448;             // 256*64
  double* C2d  = B2d + 256 * 64;           // 64*256
  double* Dxt  = C2d + 64 * 256;           // 64*448
  double* Eye2 = Dxt + 64 * 448;           // 128*128
  double* M0d  = Eye2 + 128 * 128;
  double* Rb   = M0d + 128 * 128;
  double* scv  = Rb + 128 * 128;           // 128
  float*  F32  = (float*)(scv + 128);      // 128*128
  uint*   Msh  = (uint*)(F32 + 128 * 128); // 71680
  uint*   OmWh = Msh + 71680;              // 20480
  float*  TpP  = (float*)(OmWh + 20480);   // 8128

  dim3 blk16(16, 16);
  k_xtx<<<dim3(40, 40), blk16, 0, stream>>>(X, H);
  k_prep<<<561, 256, 0, stream>>>(H, Y, B2, C2, D21, E, scv, B2d, C2d, Dxt, Eye2);

  auto inv128 = [&](const double* A, int lda, double* Out) {
    k_ginv32<<<1, 256, 0, stream>>>(A, lda, F32);
    k_cast_f2d<<<64, 256, 0, stream>>>(F32, M0d, 128 * 128);
    // one Newton-Schulz refinement: M <- M0(2I - A M0)
    k_dgemm<<<dim3(8, 8), blk16, 0, stream>>>(128, 128, 128, A, lda, M0d, 128, -1.0, Eye2, 128, 1.0, Rb, 128);
    k_dgemm<<<dim3(8, 8), blk16, 0, stream>>>(128, 128, 128, M0d, 128, Rb, 128, 1.0, (const double*)nullptr, 0, 0.0, Out, 128);
  };

  const double* EA = E;
  const double* EB = E + 128;
  const double* EC = E + 128 * 256;
  const double* ED = E + 128 * 256 + 128;

  inv128(EA, 256, Ai);
  k_dgemm<<<dim3(8, 8), blk16, 0, stream>>>(128, 128, 128, EC, 256, Ai, 128, 1.0, (const double*)nullptr, 0, 0.0, CMm, 128);
  k_dgemm<<<dim3(8, 8), blk16, 0, stream>>>(128, 128, 128, Ai, 128, EB, 256, 1.0, (const double*)nullptr, 0, 0.0, MBm, 128);
  k_dgemm<<<dim3(8, 8), blk16, 0, stream>>>(128, 128, 128, CMm, 128, EB, 256, -1.0, ED, 256, 1.0, Sm, 128);
  inv128(Sm, 128, Tm);
  k_dgemm<<<dim3(8, 8), blk16, 0, stream>>>(128, 128, 128, Tm, 128, CMm, 128, -1.0, (const double*)nullptr, 0, 0.0, Einv + 128 * 256, 256);
  k_dgemm<<<dim3(8, 8), blk16, 0, stream>>>(128, 128, 128, MBm, 128, Tm, 128, -1.0, (const double*)nullptr, 0, 0.0, Einv + 128, 256);
  k_dgemm<<<dim3(8, 8), blk16, 0, stream>>>(128, 128, 128, MBm, 128, Einv + 128 * 256, 256, -1.0, Ai, 128, 1.0, Einv, 256);
  k_copyblk<<<64, 256, 0, stream>>>(Tm, 128, Einv + 128 * 256 + 128, 256, 128 * 128, 128);

  // Axwu = Einv @ [Fm | B1 | B2]
  k_dgemm<<<dim3(24, 16), blk16, 0, stream>>>(256, 384, 256, Einv, 256, H + 384 * NTWO, NTWO, 1.0, (const double*)nullptr, 0, 0.0, Axwu, 448);
  k_dgemm<<<dim3(4, 16), blk16, 0, stream>>>(256, 64, 256, Einv, 256, B2d, 64, 1.0, (const double*)nullptr, 0, 0.0, Axwu + 384, 448);
  // G = C2 @ Axwu + [0 | D21 | 0]
  k_dgemm<<<dim3(28, 4), blk16, 0, stream>>>(64, 448, 256, C2d, 256, Axwu, 448, 1.0, Dxt, 448, 1.0, G, 448);

  k_pack<<<424, 256, 0, stream>>>(H, D12, scv, Axwu, G, Msh, OmWh, TpP);

  k_scan<<<BATCHN, 448, 0, stream>>>(u_in, Msh, OmWh, TpP, out);
}

// Round 7
// 6626.099 us; speedup vs baseline: 3.9384x; 1.1714x over previous
//
#include <hip/hip_runtime.h>
#include <math.h>
#include <stddef.h>

#define NTWO 640
#define DXN 256
#define DNLN 128
#define DINN 64
#define DOUTN 64
#define BATCHN 512
#define HORN 512
#define EPSV 1.0e-3

typedef unsigned int uint;
typedef unsigned short ushort;
typedef _Float16 half2_t __attribute__((ext_vector_type(2)));

__device__ __forceinline__ float fdot2(uint a, uint b, float c) {
#if __has_builtin(__builtin_amdgcn_fdot2)
  return __builtin_amdgcn_fdot2(__builtin_bit_cast(half2_t, a),
                                __builtin_bit_cast(half2_t, b), c, false);
#else
  half2_t x = __builtin_bit_cast(half2_t, a), y = __builtin_bit_cast(half2_t, b);
  return c + (float)x[0] * (float)y[0] + (float)x[1] * (float)y[1];
#endif
}

__device__ __forceinline__ uint pack_f16(float x, float y) {
  _Float16 hx = (_Float16)x, hy = (_Float16)y;
  ushort ux = __builtin_bit_cast(ushort, hx), uy = __builtin_bit_cast(ushort, hy);
  return ((uint)uy << 16) | (uint)ux;
}

__device__ __forceinline__ float fast_exp2(float x) {
#if __has_builtin(__builtin_amdgcn_exp2f)
  return __builtin_amdgcn_exp2f(x);
#else
  return exp2f(x);
#endif
}

__device__ __forceinline__ float bcast_lane(float v, int l) {
#if __has_builtin(__builtin_amdgcn_readlane)
  return __builtin_bit_cast(float, __builtin_amdgcn_readlane(__builtin_bit_cast(int, v), l));
#else
  return __shfl(v, l, 64);
#endif
}

// ---------------- precompute kernels (one-time, f64) ----------------

__global__ void k_xtx(const float* __restrict__ X, double* __restrict__ H) {
  __shared__ float sA[16][17];
  __shared__ float sB[16][17];
  const int tx = threadIdx.x, ty = threadIdx.y;
  const int bi = blockIdx.y * 16, bj = blockIdx.x * 16;
  double acc = 0.0;
  for (int k0 = 0; k0 < NTWO; k0 += 16) {
    sA[ty][tx] = X[(k0 + ty) * NTWO + bi + tx];
    sB[ty][tx] = X[(k0 + ty) * NTWO + bj + tx];
    __syncthreads();
#pragma unroll
    for (int kk = 0; kk < 16; ++kk)
      acc += (double)sA[kk][ty] * (double)sB[kk][tx];
    __syncthreads();
  }
  const int i = bi + ty, j = bj + tx;
  if (i == j) acc += EPSV;
  H[i * NTWO + j] = acc;
}

// fused small prep: E, sc, B2 cast, C2 cast, Dxt, Eye2
__global__ void k_prep(const double* __restrict__ H, const float* __restrict__ Y,
                       const float* __restrict__ B2, const float* __restrict__ C2,
                       const float* __restrict__ D21,
                       double* __restrict__ E, double* __restrict__ scv,
                       double* __restrict__ B2d, double* __restrict__ C2d,
                       double* __restrict__ Dxt, double* __restrict__ Eye2) {
  int idx = blockIdx.x * 256 + threadIdx.x;
  if (idx < 65536) {
    int i = idx >> 8, j = idx & 255;
    E[idx] = 0.5 * (H[i * NTWO + j] + H[(384 + i) * NTWO + 384 + j]
                    + (double)Y[i * 256 + j] - (double)Y[j * 256 + i]);
    return;
  }
  idx -= 65536;
  if (idx < 128) {
    double lam = 0.5 * H[(256 + idx) * NTWO + 256 + idx];
    scv[idx] = 2.8853900817779268 / lam;
    return;
  }
  idx -= 128;
  if (idx < 16384) { B2d[idx] = (double)B2[idx]; return; }
  idx -= 16384;
  if (idx < 16384) { C2d[idx] = (double)C2[idx]; return; }
  idx -= 16384;
  if (idx < 28672) {
    int r = idx / 448, c = idx % 448;
    double v = 0.0;
    if (c >= 256 && c < 384) v = (double)D21[r * 128 + (c - 256)];
    Dxt[idx] = v;
    return;
  }
  idx -= 28672;
  if (idx < 16384) {
    int r = idx >> 7, c = idx & 127;
    Eye2[idx] = (r == c) ? 2.0 : 0.0;
  }
}

// fp32 Gauss-Jordan inverse of 128x128 (no pivot; symmetric-part-PD input).
__global__ void k_ginv32(const double* __restrict__ A, int lda, float* __restrict__ Out) {
  __shared__ float M[128 * 129];
  const int tid = threadIdx.x;
  for (int i = tid; i < 128 * 128; i += 256)
    M[(i >> 7) * 129 + (i & 127)] = (float)A[(i >> 7) * lda + (i & 127)];
  __syncthreads();
  for (int k = 0; k < 128; ++k) {
    float ip = 1.0f / M[k * 129 + k];
    __syncthreads();
    if (tid < 128) {
      float v = M[k * 129 + tid];
      M[k * 129 + tid] = (tid == k) ? ip : v * ip;
    }
    __syncthreads();
    const int i0 = tid >> 1, half = tid & 1;
    float f = (i0 != k) ? M[i0 * 129 + k] : 0.0f;
    __syncthreads();
    if (i0 != k) {
      const float* rk = M + k * 129;
      float* ri = M + i0 * 129;
      const int j0 = half * 64;
#pragma unroll 8
      for (int j = j0; j < j0 + 64; ++j) {
        float v = (j == k) ? 0.0f : ri[j];
        ri[j] = v - f * rk[j];
      }
    }
    __syncthreads();
  }
  for (int i = tid; i < 128 * 128; i += 256) Out[i] = M[(i >> 7) * 129 + (i & 127)];
}

__global__ void k_dgemm(int M, int N, int K,
                        const double* __restrict__ A, int lda,
                        const double* __restrict__ B, int ldb,
                        double alpha,
                        const double* __restrict__ D, int ldd, double beta,
                        double* __restrict__ C, int ldc) {
  __shared__ double sA[16][17];
  __shared__ double sB[16][17];
  const int tx = threadIdx.x, ty = threadIdx.y;
  const int row = blockIdx.y * 16 + ty, col = blockIdx.x * 16 + tx;
  double acc = 0.0;
  for (int k0 = 0; k0 < K; k0 += 16) {
    sA[ty][tx] = A[row * lda + k0 + tx];
    sB[ty][tx] = B[(k0 + ty) * ldb + col];
    __syncthreads();
#pragma unroll
    for (int kk = 0; kk < 16; ++kk) acc += sA[ty][kk] * sB[kk][tx];
    __syncthreads();
  }
  double v = alpha * acc;
  if (beta != 0.0) v += beta * D[row * ldd + col];
  C[row * ldc + col] = v;
}

__global__ void k_copyblk(const double* __restrict__ S, int lds,
                          double* __restrict__ Dst, int ldd, int total, int cols) {
  int idx = blockIdx.x * 256 + threadIdx.x;
  if (idx < total) {
    int r = idx / cols, c = idx % cols;
    Dst[r * ldd + c] = S[r * lds + c];
  }
}

__global__ void k_cast_f2d(const float* __restrict__ s, double* __restrict__ d, int n) {
  int i = blockIdx.x * 256 + threadIdx.x;
  if (i < n) d[i] = (double)s[i];
}

// fused pack: Msh (448x320 f16, k-major dwords), OmWh (320x128 f16 k-major), TpP
__global__ void k_pack(const double* __restrict__ H, const float* __restrict__ D12,
                       const double* __restrict__ sc, const double* __restrict__ Axwu,
                       const double* __restrict__ G,
                       uint* __restrict__ Msh, uint* __restrict__ OmWh,
                       float* __restrict__ TpP) {
  int idx = blockIdx.x * 256 + threadIdx.x;
  if (idx < 448 * 160) {
    int rr = idx / 160, d = idx % 160;
    float v[2];
#pragma unroll
    for (int e = 0; e < 2; ++e) {
      int k = 2 * d + e;
      double x;
      if (rr < 128) {
        double s = sc[rr];
        x = (k < 256) ? (-H[(256 + rr) * NTWO + k] * s)
                      : ((double)D12[rr * DINN + (k - 256)] * s);
      } else {
        int r2 = rr - 128;
        const double* src = (r2 < 256) ? (Axwu + (size_t)r2 * 448) : (G + (size_t)(r2 - 256) * 448);
        x = (k < 256) ? src[k] : src[384 + (k - 256)];
      }
      v[e] = (float)x;
    }
    Msh[((size_t)(d >> 2) * 448 + rr) * 4 + (d & 3)] = pack_f16(v[0], v[1]);
    return;
  }
  idx -= 448 * 160;
  if (idx < 320 * 64) {
    int rr = idx / 64, d = idx % 64;
    float v[2];
#pragma unroll
    for (int e = 0; e < 2; ++e) {
      int j = 2 * d + e;
      double x = (rr < 256) ? Axwu[(size_t)rr * 448 + 256 + j]
                            : G[(size_t)(rr - 256) * 448 + 256 + j];
      v[e] = (float)x;
    }
    OmWh[((size_t)(d >> 2) * 320 + rr) * 4 + (d & 3)] = pack_f16(v[0], v[1]);
    return;
  }
  idx -= 320 * 64;
  if (idx < 16384) {
    int j = idx >> 7, c = idx & 127;
    if (c > j) {
      int pidx = 127 * j - (j * (j - 1)) / 2 + (c - j - 1);
      TpP[pidx] = (float)(-H[(256 + c) * NTWO + 256 + j] * sc[c]);
    }
  }
}

// ---------------- main scan: 256 WGs x 512 threads, NS=2, 1 WG/CU ----------------
// Base matrix (rows 0-127, 80 KB) LDS-resident. Waves 0-1: one chain per wave
// (base dots from LDS, chain in-wave). Threads 128-447: stream row `tid` of Msh
// once (shared by both samples), pre-issue OmW row; after B1 finish with w and
// write back. Threads 448-511 prefetch u. Matrix L2 traffic: 280 KB/CU/step,
// fully overlapped under the ~2.7us chain.
__global__ __launch_bounds__(512)
void k_scan(const float* __restrict__ u_in, const uint* __restrict__ Msh,
            const uint* __restrict__ OmWh, const float* __restrict__ TpP,
            float* __restrict__ out) {
  __shared__ uint4 baseL4[40 * 128];              // 80 KB: base rows k-major
  __shared__ float TpL[8128];                     // 32 KB
  __shared__ uint __align__(16) zL[2 * 164];      // z = [x(128dw);u(32dw)] x 2
  __shared__ uint __align__(16) wvhL[2 * 64];     // w f16-packed
  const int tid = threadIdx.x;
  const int s0 = blockIdx.x * 2;
  const uint4* __restrict__ mp4 = (const uint4*)Msh;
  const uint4* __restrict__ op4 = (const uint4*)OmWh;

  // one-time init
  for (int i = tid; i < 5120; i += 512) {
    const int blk = i >> 7, r = i & 127;
    baseL4[i] = mp4[(size_t)blk * 448 + r];
  }
  for (int i = tid; i < 8128; i += 512) TpL[i] = TpP[i];
  if (tid < 256) zL[(tid >> 7) * 164 + (tid & 127)] = 0u;
  if (tid < 128) out[((size_t)(s0 + (tid >> 6)) * HORN) * DOUTN + (tid & 63)] = 0.0f;
  if (tid >= 448) {
    const int i = tid - 448, s = i >> 5, k = i & 31;
    const float* up = u_in + ((size_t)(s0 + s) * HORN) * DINN + 2 * k;
    zL[s * 164 + 128 + k] = pack_f16(up[0], up[1]);
  }
  __syncthreads();

  for (int t = 0; t < HORN - 1; ++t) {
    float a0 = 0.f, a1 = 0.f;
    float unx = 0.f, uny = 0.f;
    uint4 om[16];
    if (tid < 128) {
      // ---- chain waves: base dots (LDS) + in-wave chain
      const int b = tid >> 6, l = tid & 63;
      const uint4* zz = (const uint4*)(zL + b * 164);
      float c0 = 0.f, c1 = 0.f;
#pragma unroll 8
      for (int i = 0; i < 40; ++i) {
        const uint4 mA = baseL4[i * 128 + l];
        const uint4 mB = baseL4[i * 128 + 64 + l];
        const uint4 p = zz[i];
        c0 = fdot2(mA.x, p.x, c0); c0 = fdot2(mA.y, p.y, c0);
        c0 = fdot2(mA.z, p.z, c0); c0 = fdot2(mA.w, p.w, c0);
        c1 = fdot2(mB.x, p.x, c1); c1 = fdot2(mB.y, p.y, c1);
        c1 = fdot2(mB.z, p.z, c1); c1 = fdot2(mB.w, p.w, c1);
      }
      float wx = 0.f, wy = 0.f;
      int pj = 0;
#pragma unroll 4
      for (int j = 0; j < 64; ++j) {
        const float av = bcast_lane(c0, j);
        const float sx = fast_exp2(av);
        const float rc = __builtin_amdgcn_rcpf(sx + 1.0f);
        const float w = __builtin_fmaf(-2.0f, rc, 1.0f);
        if (l == (j >> 1)) { if (j & 1) wy = w; else wx = w; }
        const float tv0 = TpL[pj + ((l > j) ? (l - j - 1) : 0)];
        c0 += ((l > j) ? tv0 : 0.0f) * w;
        c1 += TpL[pj + (l + 63 - j)] * w;
        pj += 127 - j;
      }
#pragma unroll 4
      for (int j = 64; j < 128; ++j) {
        const float av = bcast_lane(c1, j - 64);
        const float sx = fast_exp2(av);
        const float rc = __builtin_amdgcn_rcpf(sx + 1.0f);
        const float w = __builtin_fmaf(-2.0f, rc, 1.0f);
        if (l == (j >> 1)) { if (j & 1) wy = w; else wx = w; }
        const int off = l + 63 - j;
        const float tv = TpL[pj + ((off >= 0) ? off : 0)];
        c1 += ((off >= 0) ? tv : 0.0f) * w;
        pj += 127 - j;
      }
      wvhL[b * 64 + l] = pack_f16(wx, wy);
    } else if (tid < 448) {
      // ---- stream threads: row = tid (128..447), both samples, 2 batches
      const int row = tid;
      const uint4* z0 = (const uint4*)zL;
      const uint4* z1 = (const uint4*)(zL + 164);
      uint4 mbuf[20];
#pragma unroll
      for (int i = 0; i < 20; ++i) mbuf[i] = mp4[(size_t)i * 448 + row];
#pragma unroll
      for (int i = 0; i < 20; ++i) {
        const uint4 m = mbuf[i];
        const uint4 p = z0[i], q = z1[i];
        a0 = fdot2(m.x, p.x, a0); a0 = fdot2(m.y, p.y, a0);
        a0 = fdot2(m.z, p.z, a0); a0 = fdot2(m.w, p.w, a0);
        a1 = fdot2(m.x, q.x, a1); a1 = fdot2(m.y, q.y, a1);
        a1 = fdot2(m.z, q.z, a1); a1 = fdot2(m.w, q.w, a1);
      }
#pragma unroll
      for (int i = 0; i < 20; ++i) mbuf[i] = mp4[(size_t)(20 + i) * 448 + row];
#pragma unroll
      for (int i = 0; i < 20; ++i) {
        const uint4 m = mbuf[i];
        const uint4 p = z0[20 + i], q = z1[20 + i];
        a0 = fdot2(m.x, p.x, a0); a0 = fdot2(m.y, p.y, a0);
        a0 = fdot2(m.z, p.z, a0); a0 = fdot2(m.w, p.w, a0);
        a1 = fdot2(m.x, q.x, a1); a1 = fdot2(m.y, q.y, a1);
        a1 = fdot2(m.z, q.z, a1); a1 = fdot2(m.w, q.w, a1);
      }
      // pre-issue OmW row (consumed after B1)
      const int rr = row - 128;
#pragma unroll
      for (int i = 0; i < 16; ++i) om[i] = op4[(size_t)i * 320 + rr];
    } else {
      // ---- u prefetch
      const int i = tid - 448, s = i >> 5, k = i & 31;
      const float* up = u_in + ((size_t)(s0 + s) * HORN + (t + 1)) * DINN + 2 * k;
      unx = up[0]; uny = up[1];
    }
    __syncthreads();  // B1: wvh ready; stream dots done; OmW in flight

    if (tid >= 128 && tid < 448) {
      const int row = tid;
      const uint4* wp0 = (const uint4*)wvhL;
      const uint4* wp1 = (const uint4*)(wvhL + 64);
#pragma unroll
      for (int i = 0; i < 16; ++i) {
        const uint4 m = om[i];
        const uint4 p = wp0[i], q = wp1[i];
        a0 = fdot2(m.x, p.x, a0); a0 = fdot2(m.y, p.y, a0);
        a0 = fdot2(m.z, p.z, a0); a0 = fdot2(m.w, p.w, a0);
        a1 = fdot2(m.x, q.x, a1); a1 = fdot2(m.y, q.y, a1);
        a1 = fdot2(m.z, q.z, a1); a1 = fdot2(m.w, q.w, a1);
      }
      if (row < 384) {
        // x rows: pack pairs into z (even lane takes odd neighbor)
        const float n0 = __shfl_down(a0, 1, 64);
        const float n1 = __shfl_down(a1, 1, 64);
        if ((row & 1) == 0) {
          const int d = (row - 128) >> 1;
          zL[d] = pack_f16(a0, n0);
          zL[164 + d] = pack_f16(a1, n1);
        }
      } else {
        const int yr = row - 384;
        out[((size_t)s0 * HORN + (t + 1)) * DOUTN + yr] = a0;
        out[((size_t)(s0 + 1) * HORN + (t + 1)) * DOUTN + yr] = a1;
      }
    } else if (tid >= 448) {
      const int i = tid - 448, s = i >> 5, k = i & 31;
      zL[s * 164 + 128 + k] = pack_f16(unx, uny);
    }
    __syncthreads();  // B2: z ready for next step
  }
}

// ---------------- host ----------------
extern "C" void kernel_launch(void* const* d_in, const int* in_sizes, int n_in,
                              void* d_out, int out_size, void* d_ws, size_t ws_size,
                              hipStream_t stream) {
  (void)in_sizes; (void)n_in; (void)out_size; (void)ws_size;
  const float* u_in = (const float*)d_in[0];
  const float* X    = (const float*)d_in[1];
  const float* Y    = (const float*)d_in[2];
  const float* B2   = (const float*)d_in[3];
  const float* C2   = (const float*)d_in[4];
  const float* D21  = (const float*)d_in[5];
  const float* D12  = (const float*)d_in[6];
  float* out = (float*)d_out;

  double* H    = (double*)d_ws;            // 640*640
  double* E    = H + 640 * 640;            // 256*256
  double* Ai   = E + 256 * 256;            // 128*128
  double* CMm  = Ai + 128 * 128;
  double* MBm  = CMm + 128 * 128;
  double* Sm   = MBm + 128 * 128;
  double* Tm   = Sm + 128 * 128;
  double* Einv = Tm + 128 * 128;           // 256*256
  double* Axwu = Einv + 256 * 256;         // 256*448
  double* G    = Axwu + 256 * 448;         // 64*448
  double* B2d  = G + 64 * 448;             // 256*64
  double* C2d  = B2d + 256 * 64;           // 64*256
  double* Dxt  = C2d + 64 * 256;           // 64*448
  double* Eye2 = Dxt + 64 * 448;           // 128*128
  double* M0d  = Eye2 + 128 * 128;
  double* Rb   = M0d + 128 * 128;
  double* scv  = Rb + 128 * 128;           // 128
  float*  F32  = (float*)(scv + 128);      // 128*128
  uint*   Msh  = (uint*)(F32 + 128 * 128); // 71680
  uint*   OmWh = Msh + 71680;              // 20480
  float*  TpP  = (float*)(OmWh + 20480);   // 8128

  dim3 blk16(16, 16);
  k_xtx<<<dim3(40, 40), blk16, 0, stream>>>(X, H);
  k_prep<<<561, 256, 0, stream>>>(H, Y, B2, C2, D21, E, scv, B2d, C2d, Dxt, Eye2);

  auto inv128 = [&](const double* A, int lda, double* Out) {
    k_ginv32<<<1, 256, 0, stream>>>(A, lda, F32);
    k_cast_f2d<<<64, 256, 0, stream>>>(F32, M0d, 128 * 128);
    // one Newton-Schulz refinement: M <- M0(2I - A M0)
    k_dgemm<<<dim3(8, 8), blk16, 0, stream>>>(128, 128, 128, A, lda, M0d, 128, -1.0, Eye2, 128, 1.0, Rb, 128);
    k_dgemm<<<dim3(8, 8), blk16, 0, stream>>>(128, 128, 128, M0d, 128, Rb, 128, 1.0, (const double*)nullptr, 0, 0.0, Out, 128);
  };

  const double* EA = E;
  const double* EB = E + 128;
  const double* EC = E + 128 * 256;
  const double* ED = E + 128 * 256 + 128;

  inv128(EA, 256, Ai);
  k_dgemm<<<dim3(8, 8), blk16, 0, stream>>>(128, 128, 128, EC, 256, Ai, 128, 1.0, (const double*)nullptr, 0, 0.0, CMm, 128);
  k_dgemm<<<dim3(8, 8), blk16, 0, stream>>>(128, 128, 128, Ai, 128, EB, 256, 1.0, (const double*)nullptr, 0, 0.0, MBm, 128);
  k_dgemm<<<dim3(8, 8), blk16, 0, stream>>>(128, 128, 128, CMm, 128, EB, 256, -1.0, ED, 256, 1.0, Sm, 128);
  inv128(Sm, 128, Tm);
  k_dgemm<<<dim3(8, 8), blk16, 0, stream>>>(128, 128, 128, Tm, 128, CMm, 128, -1.0, (const double*)nullptr, 0, 0.0, Einv + 128 * 256, 256);
  k_dgemm<<<dim3(8, 8), blk16, 0, stream>>>(128, 128, 128, MBm, 128, Tm, 128, -1.0, (const double*)nullptr, 0, 0.0, Einv + 128, 256);
  k_dgemm<<<dim3(8, 8), blk16, 0, stream>>>(128, 128, 128, MBm, 128, Einv + 128 * 256, 256, -1.0, Ai, 128, 1.0, Einv, 256);
  k_copyblk<<<64, 256, 0, stream>>>(Tm, 128, Einv + 128 * 256 + 128, 256, 128 * 128, 128);

  // Axwu = Einv @ [Fm | B1 | B2]
  k_dgemm<<<dim3(24, 16), blk16, 0, stream>>>(256, 384, 256, Einv, 256, H + 384 * NTWO, NTWO, 1.0, (const double*)nullptr, 0, 0.0, Axwu, 448);
  k_dgemm<<<dim3(4, 16), blk16, 0, stream>>>(256, 64, 256, Einv, 256, B2d, 64, 1.0, (const double*)nullptr, 0, 0.0, Axwu + 384, 448);
  // G = C2 @ Axwu + [0 | D21 | 0]
  k_dgemm<<<dim3(28, 4), blk16, 0, stream>>>(64, 448, 256, C2d, 256, Axwu, 448, 1.0, Dxt, 448, 1.0, G, 448);

  k_pack<<<424, 256, 0, stream>>>(H, D12, scv, Axwu, G, Msh, OmWh, TpP);

  k_scan<<<BATCHN / 2, 512, 0, stream>>>(u_in, Msh, OmWh, TpP, out);
}